// Round 3
// baseline (820.039 us; speedup 1.0000x reference)
//
#include <hip/hip_runtime.h>
#include <hip/hip_bf16.h>

typedef __attribute__((ext_vector_type(8))) short short8;
typedef __attribute__((ext_vector_type(4))) float floatx4;

#define NB 64
#define NS 512
#define ND 768
#define NH 12

__device__ __forceinline__ float bf2f(unsigned short u) {
  union { unsigned int i; float f; } v; v.i = ((unsigned int)u) << 16; return v.f;
}
__device__ __forceinline__ unsigned short f2bf(float f) {
  union { float f; unsigned int i; } v; v.f = f;
  unsigned int i = v.i;
  unsigned int r = i + 0x7fffu + ((i >> 16) & 1u);
  return (unsigned short)(r >> 16);
}

// async global->LDS, 16B per lane. LDS dest is wave-uniform base + lane*16.
__device__ __forceinline__ void gload_lds16(const unsigned short* g, unsigned short* l) {
  __builtin_amdgcn_global_load_lds(
      (const __attribute__((address_space(1))) unsigned int*)g,
      (__attribute__((address_space(3))) unsigned int*)l, 16, 0, 0);
}

#define WAITV(n) asm volatile("s_waitcnt vmcnt(" #n ")" ::: "memory")
#define CFENCE() asm volatile("" ::: "memory")

// ------- fp32 -> bf16 convert: 4 elements/thread -------
__global__ void convert_k(const float* __restrict__ src, unsigned short* __restrict__ dst,
                          int n4) {
  int i = blockIdx.x * 256 + threadIdx.x;
  if (i >= n4) return;
  float4 v = ((const float4*)src)[i];
  ushort4 o;
  o.x = f2bf(v.x); o.y = f2bf(v.y); o.z = f2bf(v.z); o.w = f2bf(v.w);
  ((ushort4*)dst)[i] = o;
}

// ------- transpose + convert: in (R x C fp32) -> out (C x R bf16) ----
__global__ void transpose_cvt_k(const float* __restrict__ in, unsigned short* __restrict__ out,
                                int R, int C) {
  __shared__ unsigned short tile[32][33];
  int c0 = blockIdx.x * 32, r0 = blockIdx.y * 32;
  int tx = threadIdx.x, ty = threadIdx.y;
#pragma unroll
  for (int i = 0; i < 32; i += 8)
    tile[ty + i][tx] = f2bf(in[(r0 + ty + i) * C + c0 + tx]);
  __syncthreads();
#pragma unroll
  for (int i = 0; i < 32; i += 8) out[(c0 + ty + i) * R + r0 + tx] = tile[tx][ty + i];
}

// ---------------- GEMM: C = A(MxK bf16) * Bt(NxK bf16)^T + bias(fp32) ----------------
// 256x256 tile, BK=32, 8 waves (2M x 4N), 4-slot LDS ring, counted vmcnt(8) pipeline,
// XOR chunk swizzle on stage-source + frag-read, setprio around MFMA, XCD block swizzle.
// MODE 0: fp32 store to out[m*N+n].
// MODE 1: bf16 scatter into Q/K (B,H,S,64) WITH FUSED ROPE, Vt (B,H,64,S) plain.
template <int MODE>
__global__ __launch_bounds__(512, 2) void gemm_k(
    const unsigned short* __restrict__ A, const unsigned short* __restrict__ Bt,
    const float* __restrict__ bias, float* __restrict__ out,
    unsigned short* __restrict__ Qg, unsigned short* __restrict__ Kg,
    unsigned short* __restrict__ Vtg, int M, int N, int K) {
  __shared__ unsigned short As[4][8192];  // 4 ring slots x (256 rows x 32 bf16) = 4 x 16KB
  __shared__ unsigned short Bs[4][8192];

  // XCD-aware swizzle (nwg % 8 == 0: QKV 1152, proj 384)
  int nbx = N >> 8;
  int nwg = (M >> 8) * nbx;
  int id = blockIdx.x;
  int q8 = nwg >> 3;
  int wg = (id & 7) * q8 + (id >> 3);
  int bx = wg % nbx, by = wg / nbx;
  int n0 = bx * 256, m0 = by * 256;

  int t = threadIdx.x;
  int w = t >> 6, lane = t & 63;
  int wm = (w >> 2) * 128, wn = (w & 3) * 64;  // wave owns 128x64 of C
  int lr = lane & 15, lq = lane >> 4;

  // staging (global source carries the inverse swizzle; LDS dest linear)
  int srow = w * 16 + (lane >> 2);
  int sch = ((lane & 3) ^ ((lane >> 3) & 3)) * 8;
  const unsigned short* a0 = A + (size_t)(m0 + srow) * K + sch;
  const unsigned short* b0 = Bt + (size_t)(n0 + srow) * K + sch;
  const size_t half = (size_t)128 * K;
  int ldsoff = w * 512;

  // fragment-read addresses (same involution on chunk)
  int cs = (lq ^ ((lr >> 1) & 3)) * 8;
  int rA = (wm + lr) * 32 + cs;
  int rB = (wn + lr) * 32 + cs;

  floatx4 acc[8][4];
#pragma unroll
  for (int i = 0; i < 8; i++)
#pragma unroll
    for (int j = 0; j < 4; j++) acc[i][j] = (floatx4){0.f, 0.f, 0.f, 0.f};

  const int NKT = K >> 5;  // 24 for K=768

#define STAGE(kt_)                                                  \
  {                                                                 \
    int s_ = (kt_) & 3;                                             \
    const unsigned short* ak_ = a0 + (kt_) * 32;                    \
    const unsigned short* bk_ = b0 + (kt_) * 32;                    \
    gload_lds16(ak_, &As[s_][ldsoff]);                              \
    gload_lds16(ak_ + half, &As[s_][4096 + ldsoff]);                \
    gload_lds16(bk_, &Bs[s_][ldsoff]);                              \
    gload_lds16(bk_ + half, &Bs[s_][4096 + ldsoff]);                \
  }

#define COMPUTE(kt_)                                                            \
  {                                                                             \
    int s_ = (kt_) & 3;                                                         \
    short8 bfr[4], af[8];                                                       \
    _Pragma("unroll") for (int nf = 0; nf < 4; nf++)                            \
        bfr[nf] = *(const short8*)&Bs[s_][rB + nf * 512];                       \
    _Pragma("unroll") for (int mf = 0; mf < 8; mf++)                            \
        af[mf] = *(const short8*)&As[s_][rA + mf * 512];                        \
    __builtin_amdgcn_s_setprio(1);                                              \
    _Pragma("unroll") for (int mf = 0; mf < 8; mf++)                            \
        _Pragma("unroll") for (int nf = 0; nf < 4; nf++)                        \
            acc[mf][nf] =                                                       \
        __builtin_amdgcn_mfma_f32_16x16x32_bf16(af[mf], bfr[nf], acc[mf][nf],   \
                                                0, 0, 0);                       \
    __builtin_amdgcn_s_setprio(0);                                              \
  }

  STAGE(0);
  STAGE(1);
  STAGE(2);
  for (int kt = 0; kt < NKT - 3; ++kt) {
    WAITV(8);
    __builtin_amdgcn_s_barrier();
    CFENCE();
    STAGE(kt + 3);
    COMPUTE(kt);
  }
  WAITV(8); __builtin_amdgcn_s_barrier(); CFENCE(); COMPUTE(NKT - 3);
  WAITV(4); __builtin_amdgcn_s_barrier(); CFENCE(); COMPUTE(NKT - 2);
  WAITV(0); __builtin_amdgcn_s_barrier(); CFENCE(); COMPUTE(NKT - 1);
#undef STAGE
#undef COMPUTE

  // ---------------- epilogue ----------------
  float bv[4];
#pragma unroll
  for (int nf = 0; nf < 4; nf++) bv[nf] = bias[n0 + wn + nf * 16 + lr];

  int part = 0, h = 0;
  float ivf0 = 0.f, ivf1 = 0.f;
  if (MODE == 1) {
    int nbase = n0 + wn;            // wave-uniform, 64-aligned => one head, one part
    part = nbase / ND;
    h = (nbase - part * ND) >> 6;
    ivf0 = __expf(-(float)lr * 0.28782313662425572f);         // invfreq(d=lr)
    ivf1 = __expf(-(float)(16 + lr) * 0.28782313662425572f);  // invfreq(d=16+lr)
  }

#pragma unroll
  for (int mf = 0; mf < 8; mf++) {
#pragma unroll
    for (int r = 0; r < 4; r++) {
      int m = m0 + wm + mf * 16 + lq * 4 + r;  // C/D: row=(lane>>4)*4+reg, col=lane&15
      float fo[4];
#pragma unroll
      for (int nf = 0; nf < 4; nf++) fo[nf] = acc[mf][nf][r] + bv[nf];
      if (MODE == 0) {
#pragma unroll
        for (int nf = 0; nf < 4; nf++)
          out[(size_t)m * N + (n0 + wn + nf * 16 + lr)] = fo[nf];
      } else {
        int b = m >> 9, s = m & 511;
        int bh = b * NH + h;
        if (part == 2) {
#pragma unroll
          for (int nf = 0; nf < 4; nf++)
            Vtg[((size_t)bh * 64 + nf * 16 + lr) * NS + s] = f2bf(fo[nf]);
        } else {
          // fused RoPE: head cols c = nf*16+lr; outputs (d, d+32) need inputs (2d, 2d+1).
          // col c<32 -> d=c; inputs at cols 2c,2c+1 held by lane (2lr)&15 / (2lr+1)&15,
          // reg pair (fo0,fo1) for c=lr (low) and (fo2,fo3) for c=16+lr (high).
          unsigned short* dst = (part ? Kg : Qg) + ((size_t)bh * NS + s) * 64;
          int sl0 = (lq << 4) | ((2 * lr) & 15);
          int sl1 = (lq << 4) | ((2 * lr + 1) & 15);
          float a_l = __shfl(fo[0], sl0), a_h = __shfl(fo[1], sl0);
          float b_l = __shfl(fo[0], sl1), b_h = __shfl(fo[1], sl1);
          float c_l = __shfl(fo[2], sl0), c_h = __shfl(fo[3], sl0);
          float d_l = __shfl(fo[2], sl1), d_h = __shfl(fo[3], sl1);
          bool lo = lr < 8;
          float Av = lo ? a_l : a_h, Bv = lo ? b_l : b_h;   // in(2lr), in(2lr+1)
          float Cv = lo ? c_l : c_h, Dv = lo ? d_l : d_h;   // in(32+2lr), in(33+2lr)
          float fs = (float)s;
          float sn0, cs0, sn1, cs1;
          __sincosf(fs * ivf0, &sn0, &cs0);
          __sincosf(fs * ivf1, &sn1, &cs1);
          dst[lr]      = f2bf(Av * cs0 - Bv * sn0);  // d = lr
          dst[16 + lr] = f2bf(Cv * cs1 - Dv * sn1);  // d = 16+lr
          dst[32 + lr] = f2bf(Av * sn0 + Bv * cs0);  // d+32
          dst[48 + lr] = f2bf(Cv * sn1 + Dv * cs1);  // d+32
        }
      }
    }
  }
}

// ---------------- flash attention: 1 WG = (b,h) x 64 q-rows ----------------
// No K/V LDS staging (K/V are L2-resident: 128KB per bh), no barriers at all.
// Ps is per-wave scratch for the P-fragment transpose; per-wave LDS ordering only.
__global__ __launch_bounds__(256) void attn_k(
    const unsigned short* __restrict__ Qg, const unsigned short* __restrict__ Kg,
    const unsigned short* __restrict__ Vtg, unsigned short* __restrict__ ctx) {
  __shared__ unsigned short Ps[4][16 * 72];
  int qt = blockIdx.x, bh = blockIdx.y;
  int t = threadIdx.x, w = t >> 6, lane = t & 63;
  int lr = lane & 15, lq = lane >> 4;
  int q0 = qt * 64 + w * 16;
  const unsigned short* Qb = Qg + (bh * NS + q0) * 64;
  short8 qf0 = *(const short8*)&Qb[lr * 64 + lq * 8];
  short8 qf1 = *(const short8*)&Qb[lr * 64 + 32 + lq * 8];
  floatx4 o[4];
#pragma unroll
  for (int ft = 0; ft < 4; ft++) o[ft] = (floatx4){0.f, 0.f, 0.f, 0.f};
  float m_[4] = {-1e30f, -1e30f, -1e30f, -1e30f};
  float l_[4] = {0.f, 0.f, 0.f, 0.f};
  const unsigned short* Kb = Kg + bh * NS * 64;
  const unsigned short* Vb = Vtg + bh * 64 * NS;

  for (int kt = 0; kt < 8; kt++) {
    floatx4 sf[4];
#pragma unroll
    for (int nt = 0; nt < 4; nt++) sf[nt] = (floatx4){0.f, 0.f, 0.f, 0.f};
#pragma unroll
    for (int nt = 0; nt < 4; nt++) {
      short8 k0 = *(const short8*)&Kb[(kt * 64 + nt * 16 + lr) * 64 + lq * 8];
      short8 k1 = *(const short8*)&Kb[(kt * 64 + nt * 16 + lr) * 64 + 32 + lq * 8];
      sf[nt] = __builtin_amdgcn_mfma_f32_16x16x32_bf16(qf0, k0, sf[nt], 0, 0, 0);
      sf[nt] = __builtin_amdgcn_mfma_f32_16x16x32_bf16(qf1, k1, sf[nt], 0, 0, 0);
    }
    float alpha[4];
#pragma unroll
    for (int r = 0; r < 4; r++) {
      float v = fmaxf(fmaxf(sf[0][r], sf[1][r]), fmaxf(sf[2][r], sf[3][r])) * 0.125f;
      v = fmaxf(v, __shfl_xor(v, 1));
      v = fmaxf(v, __shfl_xor(v, 2));
      v = fmaxf(v, __shfl_xor(v, 4));
      v = fmaxf(v, __shfl_xor(v, 8));
      float mn = fmaxf(m_[r], v);
      alpha[r] = __expf(m_[r] - mn);
      m_[r] = mn;
    }
    float rsum[4] = {0.f, 0.f, 0.f, 0.f};
#pragma unroll
    for (int nt = 0; nt < 4; nt++)
#pragma unroll
      for (int r = 0; r < 4; r++) {
        float pv = __expf(sf[nt][r] * 0.125f - m_[r]);
        rsum[r] += pv;
        Ps[w][(lq * 4 + r) * 72 + nt * 16 + lr] = f2bf(pv);
      }
#pragma unroll
    for (int r = 0; r < 4; r++) {
      float v = rsum[r];
      v += __shfl_xor(v, 1);
      v += __shfl_xor(v, 2);
      v += __shfl_xor(v, 4);
      v += __shfl_xor(v, 8);
      l_[r] = l_[r] * alpha[r] + v;
    }
#pragma unroll
    for (int ft = 0; ft < 4; ft++)
#pragma unroll
      for (int r = 0; r < 4; r++) o[ft][r] *= alpha[r];
    // per-wave LDS RAW fence: Ps writes above -> Ps reads below (same wave, diff lanes)
    asm volatile("s_waitcnt lgkmcnt(0)" ::: "memory");
    __builtin_amdgcn_sched_barrier(0);
#pragma unroll
    for (int ks = 0; ks < 2; ks++) {
      short8 pf = *(const short8*)&Ps[w][lr * 72 + ks * 32 + lq * 8];
#pragma unroll
      for (int ft = 0; ft < 4; ft++) {
        short8 vf = *(const short8*)&Vb[(ft * 16 + lr) * NS + kt * 64 + ks * 32 + lq * 8];
        o[ft] = __builtin_amdgcn_mfma_f32_16x16x32_bf16(pf, vf, o[ft], 0, 0, 0);
      }
    }
  }
  int b = bh / NH, h = bh - (bh / NH) * NH;
#pragma unroll
  for (int r = 0; r < 4; r++) {
    float inv = 1.f / l_[r];
#pragma unroll
    for (int ft = 0; ft < 4; ft++)
      ctx[(b * NS + q0 + lq * 4 + r) * ND + h * 64 + ft * 16 + lr] = f2bf(o[ft][r] * inv);
  }
}

extern "C" void kernel_launch(void* const* d_in, const int* in_sizes, int n_in,
                              void* d_out, int out_size, void* d_ws, size_t ws_size,
                              hipStream_t stream) {
  const float* x     = (const float*)d_in[0];   // fp32 (confirmed: bf16 read -> NaN)
  const float* w_qkv = (const float*)d_in[1];   // (768, 2304) fp32
  const float* b_qkv = (const float*)d_in[2];
  const float* w_o   = (const float*)d_in[3];   // (768, 768) fp32
  const float* b_o   = (const float*)d_in[4];
  float* out = (float*)d_out;                   // fp32: reference output dtype

  char* ws = (char*)d_ws;
  unsigned short* xb    = (unsigned short*)(ws);              // x bf16; reused as ctx
  unsigned short* wqkvT = (unsigned short*)(ws + 50331648);   // 2304x768 bf16
  unsigned short* woT   = (unsigned short*)(ws + 53870592);   // 768x768 bf16
  unsigned short* Qg    = (unsigned short*)(ws + 55050240);   // (B,H,S,64) bf16, roped
  unsigned short* Kg    = (unsigned short*)(ws + 105381888);  // roped
  unsigned short* Vtg   = (unsigned short*)(ws + 155713536);
  unsigned short* ctx   = xb;  // x dead after QKV GEMM

  transpose_cvt_k<<<dim3(2304 / 32, 768 / 32), dim3(32, 8), 0, stream>>>(w_qkv, wqkvT, 768, 2304);
  transpose_cvt_k<<<dim3(768 / 32, 768 / 32), dim3(32, 8), 0, stream>>>(w_o, woT, 768, 768);
  convert_k<<<24576, 256, 0, stream>>>(x, xb, 6291456);
  gemm_k<1><<<dim3((32768 / 256) * (2304 / 256)), dim3(512), 0, stream>>>(
      xb, wqkvT, b_qkv, nullptr, Qg, Kg, Vtg, 32768, 2304, 768);
  attn_k<<<dim3(NS / 64, NB * NH), dim3(256), 0, stream>>>(Qg, Kg, Vtg, ctx);
  gemm_k<0><<<dim3((32768 / 256) * (768 / 256)), dim3(512), 0, stream>>>(
      ctx, woT, b_o, out, nullptr, nullptr, nullptr, 32768, 768, 768);
}

// Round 4
// 653.921 us; speedup vs baseline: 1.2540x; 1.2540x over previous
//
#include <hip/hip_runtime.h>
#include <hip/hip_bf16.h>

typedef __attribute__((ext_vector_type(8))) short short8;
typedef __attribute__((ext_vector_type(4))) float floatx4;

#define NB 64
#define NS 512
#define ND 768
#define NH 12

__device__ __forceinline__ float bf2f(unsigned short u) {
  union { unsigned int i; float f; } v; v.i = ((unsigned int)u) << 16; return v.f;
}
__device__ __forceinline__ unsigned short f2bf(float f) {
  union { float f; unsigned int i; } v; v.f = f;
  unsigned int i = v.i;
  unsigned int r = i + 0x7fffu + ((i >> 16) & 1u);
  return (unsigned short)(r >> 16);
}

// async global->LDS, 16B per lane. LDS dest is wave-uniform base + lane*16.
__device__ __forceinline__ void gload_lds16(const unsigned short* g, unsigned short* l) {
  __builtin_amdgcn_global_load_lds(
      (const __attribute__((address_space(1))) unsigned int*)g,
      (__attribute__((address_space(3))) unsigned int*)l, 16, 0, 0);
}

#define WAITV(n) asm volatile("s_waitcnt vmcnt(" #n ")" ::: "memory")
#define CFENCE() asm volatile("" ::: "memory")

// ------- fp32 -> bf16 convert: 4 elements/thread -------
__global__ void convert_k(const float* __restrict__ src, unsigned short* __restrict__ dst,
                          int n4) {
  int i = blockIdx.x * 256 + threadIdx.x;
  if (i >= n4) return;
  float4 v = ((const float4*)src)[i];
  ushort4 o;
  o.x = f2bf(v.x); o.y = f2bf(v.y); o.z = f2bf(v.z); o.w = f2bf(v.w);
  ((ushort4*)dst)[i] = o;
}

// ------- transpose + convert: in (R x C fp32) -> out (C x R bf16) ----
__global__ void transpose_cvt_k(const float* __restrict__ in, unsigned short* __restrict__ out,
                                int R, int C) {
  __shared__ unsigned short tile[32][33];
  int c0 = blockIdx.x * 32, r0 = blockIdx.y * 32;
  int tx = threadIdx.x, ty = threadIdx.y;
#pragma unroll
  for (int i = 0; i < 32; i += 8)
    tile[ty + i][tx] = f2bf(in[(r0 + ty + i) * C + c0 + tx]);
  __syncthreads();
#pragma unroll
  for (int i = 0; i < 32; i += 8) out[(c0 + ty + i) * R + r0 + tx] = tile[tx][ty + i];
}

// ---------------- GEMM: C = A(MxK bf16) * Bt(NxK bf16)^T + bias(fp32) ----------------
// 256x256 tile, BK=32, 8 waves (2M x 4N), 4-slot LDS ring, counted vmcnt(8) pipeline,
// XOR chunk swizzle on stage-source + frag-read, setprio around MFMA, XCD block swizzle.
// MODE 0: fp32 store to out[m*N+n].
// MODE 1: bf16 scatter into Q/K (B,H,S,64) WITH FUSED ROPE, Vt (B,H,64,S) plain.
template <int MODE>
__global__ __launch_bounds__(512, 2) void gemm_k(
    const unsigned short* __restrict__ A, const unsigned short* __restrict__ Bt,
    const float* __restrict__ bias, float* __restrict__ out,
    unsigned short* __restrict__ Qg, unsigned short* __restrict__ Kg,
    unsigned short* __restrict__ Vtg, int M, int N, int K) {
  __shared__ unsigned short As[4][8192];  // 4 ring slots x (256 rows x 32 bf16) = 4 x 16KB
  __shared__ unsigned short Bs[4][8192];

  // XCD-aware swizzle (nwg % 8 == 0: QKV 1152, proj 384)
  int nbx = N >> 8;
  int nwg = (M >> 8) * nbx;
  int id = blockIdx.x;
  int q8 = nwg >> 3;
  int wg = (id & 7) * q8 + (id >> 3);
  int bx = wg % nbx, by = wg / nbx;
  int n0 = bx * 256, m0 = by * 256;

  int t = threadIdx.x;
  int w = t >> 6, lane = t & 63;
  int wm = (w >> 2) * 128, wn = (w & 3) * 64;  // wave owns 128x64 of C
  int lr = lane & 15, lq = lane >> 4;

  // staging (global source carries the inverse swizzle; LDS dest linear)
  int srow = w * 16 + (lane >> 2);
  int sch = ((lane & 3) ^ ((lane >> 3) & 3)) * 8;
  const unsigned short* a0 = A + (size_t)(m0 + srow) * K + sch;
  const unsigned short* b0 = Bt + (size_t)(n0 + srow) * K + sch;
  const size_t half = (size_t)128 * K;
  int ldsoff = w * 512;

  // fragment-read addresses (same involution on chunk)
  int cs = (lq ^ ((lr >> 1) & 3)) * 8;
  int rA = (wm + lr) * 32 + cs;
  int rB = (wn + lr) * 32 + cs;

  floatx4 acc[8][4];
#pragma unroll
  for (int i = 0; i < 8; i++)
#pragma unroll
    for (int j = 0; j < 4; j++) acc[i][j] = (floatx4){0.f, 0.f, 0.f, 0.f};

  const int NKT = K >> 5;  // 24 for K=768

#define STAGE(kt_)                                                  \
  {                                                                 \
    int s_ = (kt_) & 3;                                             \
    const unsigned short* ak_ = a0 + (kt_) * 32;                    \
    const unsigned short* bk_ = b0 + (kt_) * 32;                    \
    gload_lds16(ak_, &As[s_][ldsoff]);                              \
    gload_lds16(ak_ + half, &As[s_][4096 + ldsoff]);                \
    gload_lds16(bk_, &Bs[s_][ldsoff]);                              \
    gload_lds16(bk_ + half, &Bs[s_][4096 + ldsoff]);                \
  }

#define COMPUTE(kt_)                                                            \
  {                                                                             \
    int s_ = (kt_) & 3;                                                         \
    short8 bfr[4], af[8];                                                       \
    _Pragma("unroll") for (int nf = 0; nf < 4; nf++)                            \
        bfr[nf] = *(const short8*)&Bs[s_][rB + nf * 512];                       \
    _Pragma("unroll") for (int mf = 0; mf < 8; mf++)                            \
        af[mf] = *(const short8*)&As[s_][rA + mf * 512];                        \
    __builtin_amdgcn_s_setprio(1);                                              \
    _Pragma("unroll") for (int mf = 0; mf < 8; mf++)                            \
        _Pragma("unroll") for (int nf = 0; nf < 4; nf++)                        \
            acc[mf][nf] =                                                       \
        __builtin_amdgcn_mfma_f32_16x16x32_bf16(af[mf], bfr[nf], acc[mf][nf],   \
                                                0, 0, 0);                       \
    __builtin_amdgcn_s_setprio(0);                                              \
  }

  STAGE(0);
  STAGE(1);
  STAGE(2);
  for (int kt = 0; kt < NKT - 3; ++kt) {
    WAITV(8);
    __builtin_amdgcn_s_barrier();
    CFENCE();
    STAGE(kt + 3);
    COMPUTE(kt);
  }
  WAITV(8); __builtin_amdgcn_s_barrier(); CFENCE(); COMPUTE(NKT - 3);
  WAITV(4); __builtin_amdgcn_s_barrier(); CFENCE(); COMPUTE(NKT - 2);
  WAITV(0); __builtin_amdgcn_s_barrier(); CFENCE(); COMPUTE(NKT - 1);
#undef STAGE
#undef COMPUTE

  // ---------------- epilogue ----------------
  float bv[4];
#pragma unroll
  for (int nf = 0; nf < 4; nf++) bv[nf] = bias[n0 + wn + nf * 16 + lr];

  int part = 0, h = 0;
  float ivf0 = 0.f, ivf1 = 0.f;
  if (MODE == 1) {
    int nbase = n0 + wn;            // wave-uniform, 64-aligned => one head, one part
    part = nbase / ND;
    h = (nbase - part * ND) >> 6;
    ivf0 = __expf(-(float)lr * 0.28782313662425572f);         // invfreq(d=lr)
    ivf1 = __expf(-(float)(16 + lr) * 0.28782313662425572f);  // invfreq(d=16+lr)
  }

#pragma unroll
  for (int mf = 0; mf < 8; mf++) {
#pragma unroll
    for (int r = 0; r < 4; r++) {
      int m = m0 + wm + mf * 16 + lq * 4 + r;  // C/D: row=(lane>>4)*4+reg, col=lane&15
      float fo[4];
#pragma unroll
      for (int nf = 0; nf < 4; nf++) fo[nf] = acc[mf][nf][r] + bv[nf];
      if (MODE == 0) {
#pragma unroll
        for (int nf = 0; nf < 4; nf++)
          out[(size_t)m * N + (n0 + wn + nf * 16 + lr)] = fo[nf];
      } else {
        int b = m >> 9, s = m & 511;
        int bh = b * NH + h;
        if (part == 2) {
#pragma unroll
          for (int nf = 0; nf < 4; nf++)
            Vtg[((size_t)bh * 64 + nf * 16 + lr) * NS + s] = f2bf(fo[nf]);
        } else {
          // fused RoPE: head cols c = nf*16+lr; outputs (d, d+32) need inputs (2d, 2d+1).
          unsigned short* dst = (part ? Kg : Qg) + ((size_t)bh * NS + s) * 64;
          int sl0 = (lq << 4) | ((2 * lr) & 15);
          int sl1 = (lq << 4) | ((2 * lr + 1) & 15);
          float a_l = __shfl(fo[0], sl0), a_h = __shfl(fo[1], sl0);
          float b_l = __shfl(fo[0], sl1), b_h = __shfl(fo[1], sl1);
          float c_l = __shfl(fo[2], sl0), c_h = __shfl(fo[3], sl0);
          float d_l = __shfl(fo[2], sl1), d_h = __shfl(fo[3], sl1);
          bool lo = lr < 8;
          float Av = lo ? a_l : a_h, Bv = lo ? b_l : b_h;   // in(2lr), in(2lr+1)
          float Cv = lo ? c_l : c_h, Dv = lo ? d_l : d_h;   // in(32+2lr), in(33+2lr)
          float fs = (float)s;
          float sn0, cs0, sn1, cs1;
          __sincosf(fs * ivf0, &sn0, &cs0);
          __sincosf(fs * ivf1, &sn1, &cs1);
          dst[lr]      = f2bf(Av * cs0 - Bv * sn0);  // d = lr
          dst[16 + lr] = f2bf(Cv * cs1 - Dv * sn1);  // d = 16+lr
          dst[32 + lr] = f2bf(Av * sn0 + Bv * cs0);  // d+32
          dst[48 + lr] = f2bf(Cv * sn1 + Dv * cs1);  // d+32
        }
      }
    }
  }
}

// ---------------- flash attention: 1 WG = (b,h) x 64 q-rows, LDS-staged K/V ----------------
// Grid = (bh, qt): linear id = bh + qt*768, 768 % 8 == 0 -> all qt-blocks of one bh land on
// the SAME XCD, so K/V is HBM-fetched once and L2-served for the other 7 blocks.
__global__ __launch_bounds__(256) void attn_k(
    const unsigned short* __restrict__ Qg, const unsigned short* __restrict__ Kg,
    const unsigned short* __restrict__ Vtg, unsigned short* __restrict__ ctx) {
  __shared__ unsigned short Ks[64 * 72];
  __shared__ unsigned short Vs[64 * 72];
  __shared__ unsigned short Ps[4][16 * 72];
  int bh = blockIdx.x, qt = blockIdx.y;
  int t = threadIdx.x, w = t >> 6, lane = t & 63;
  int lr = lane & 15, lq = lane >> 4;
  int q0 = qt * 64 + w * 16;
  const unsigned short* Qb = Qg + (bh * NS + q0) * 64;
  short8 qf0 = *(const short8*)&Qb[lr * 64 + lq * 8];
  short8 qf1 = *(const short8*)&Qb[lr * 64 + 32 + lq * 8];
  floatx4 o[4];
#pragma unroll
  for (int ft = 0; ft < 4; ft++) o[ft] = (floatx4){0.f, 0.f, 0.f, 0.f};
  float m_[4] = {-1e30f, -1e30f, -1e30f, -1e30f};
  float l_[4] = {0.f, 0.f, 0.f, 0.f};
  int srow = t >> 2, scc = t & 3;
  const unsigned short* Kb = Kg + bh * NS * 64;
  const unsigned short* Vb = Vtg + bh * 64 * NS;

  for (int kt = 0; kt < 8; kt++) {
    __syncthreads();
    *(short8*)&Ks[srow * 72 + scc * 8]      = *(const short8*)&Kb[(kt * 64 + srow) * 64 + scc * 8];
    *(short8*)&Ks[srow * 72 + 32 + scc * 8] = *(const short8*)&Kb[(kt * 64 + srow) * 64 + 32 + scc * 8];
    *(short8*)&Vs[srow * 72 + scc * 8]      = *(const short8*)&Vb[srow * NS + kt * 64 + scc * 8];
    *(short8*)&Vs[srow * 72 + 32 + scc * 8] = *(const short8*)&Vb[srow * NS + kt * 64 + 32 + scc * 8];
    __syncthreads();

    floatx4 sf[4];
#pragma unroll
    for (int nt = 0; nt < 4; nt++) sf[nt] = (floatx4){0.f, 0.f, 0.f, 0.f};
#pragma unroll
    for (int nt = 0; nt < 4; nt++) {
      short8 k0 = *(const short8*)&Ks[(nt * 16 + lr) * 72 + lq * 8];
      short8 k1 = *(const short8*)&Ks[(nt * 16 + lr) * 72 + 32 + lq * 8];
      sf[nt] = __builtin_amdgcn_mfma_f32_16x16x32_bf16(qf0, k0, sf[nt], 0, 0, 0);
      sf[nt] = __builtin_amdgcn_mfma_f32_16x16x32_bf16(qf1, k1, sf[nt], 0, 0, 0);
    }
    float alpha[4];
#pragma unroll
    for (int r = 0; r < 4; r++) {
      float v = fmaxf(fmaxf(sf[0][r], sf[1][r]), fmaxf(sf[2][r], sf[3][r])) * 0.125f;
      v = fmaxf(v, __shfl_xor(v, 1));
      v = fmaxf(v, __shfl_xor(v, 2));
      v = fmaxf(v, __shfl_xor(v, 4));
      v = fmaxf(v, __shfl_xor(v, 8));
      float mn = fmaxf(m_[r], v);
      alpha[r] = __expf(m_[r] - mn);
      m_[r] = mn;
    }
    float rsum[4] = {0.f, 0.f, 0.f, 0.f};
#pragma unroll
    for (int nt = 0; nt < 4; nt++)
#pragma unroll
      for (int r = 0; r < 4; r++) {
        float pv = __expf(sf[nt][r] * 0.125f - m_[r]);
        rsum[r] += pv;
        Ps[w][(lq * 4 + r) * 72 + nt * 16 + lr] = f2bf(pv);
      }
#pragma unroll
    for (int r = 0; r < 4; r++) {
      float v = rsum[r];
      v += __shfl_xor(v, 1);
      v += __shfl_xor(v, 2);
      v += __shfl_xor(v, 4);
      v += __shfl_xor(v, 8);
      l_[r] = l_[r] * alpha[r] + v;
    }
#pragma unroll
    for (int ft = 0; ft < 4; ft++)
#pragma unroll
      for (int r = 0; r < 4; r++) o[ft][r] *= alpha[r];
#pragma unroll
    for (int ks = 0; ks < 2; ks++) {
      short8 pf = *(const short8*)&Ps[w][lr * 72 + ks * 32 + lq * 8];
#pragma unroll
      for (int ft = 0; ft < 4; ft++) {
        short8 vf = *(const short8*)&Vs[(ft * 16 + lr) * 72 + ks * 32 + lq * 8];
        o[ft] = __builtin_amdgcn_mfma_f32_16x16x32_bf16(pf, vf, o[ft], 0, 0, 0);
      }
    }
  }
  int b = bh / NH, h = bh - (bh / NH) * NH;
#pragma unroll
  for (int r = 0; r < 4; r++) {
    float inv = 1.f / l_[r];
#pragma unroll
    for (int ft = 0; ft < 4; ft++)
      ctx[(b * NS + q0 + lq * 4 + r) * ND + h * 64 + ft * 16 + lr] = f2bf(o[ft][r] * inv);
  }
}

extern "C" void kernel_launch(void* const* d_in, const int* in_sizes, int n_in,
                              void* d_out, int out_size, void* d_ws, size_t ws_size,
                              hipStream_t stream) {
  const float* x     = (const float*)d_in[0];   // fp32 (confirmed: bf16 read -> NaN)
  const float* w_qkv = (const float*)d_in[1];   // (768, 2304) fp32
  const float* b_qkv = (const float*)d_in[2];
  const float* w_o   = (const float*)d_in[3];   // (768, 768) fp32
  const float* b_o   = (const float*)d_in[4];
  float* out = (float*)d_out;                   // fp32: reference output dtype

  char* ws = (char*)d_ws;
  unsigned short* xb    = (unsigned short*)(ws);              // x bf16; reused as ctx
  unsigned short* wqkvT = (unsigned short*)(ws + 50331648);   // 2304x768 bf16
  unsigned short* woT   = (unsigned short*)(ws + 53870592);   // 768x768 bf16
  unsigned short* Qg    = (unsigned short*)(ws + 55050240);   // (B,H,S,64) bf16, roped
  unsigned short* Kg    = (unsigned short*)(ws + 105381888);  // roped
  unsigned short* Vtg   = (unsigned short*)(ws + 155713536);
  unsigned short* ctx   = xb;  // x dead after QKV GEMM

  transpose_cvt_k<<<dim3(2304 / 32, 768 / 32), dim3(32, 8), 0, stream>>>(w_qkv, wqkvT, 768, 2304);
  transpose_cvt_k<<<dim3(768 / 32, 768 / 32), dim3(32, 8), 0, stream>>>(w_o, woT, 768, 768);
  convert_k<<<24576, 256, 0, stream>>>(x, xb, 6291456);
  gemm_k<1><<<dim3((32768 / 256) * (2304 / 256)), dim3(512), 0, stream>>>(
      xb, wqkvT, b_qkv, nullptr, Qg, Kg, Vtg, 32768, 2304, 768);
  attn_k<<<dim3(NB * NH, NS / 64), dim3(256), 0, stream>>>(Qg, Kg, Vtg, ctx);
  gemm_k<0><<<dim3((32768 / 256) * (768 / 256)), dim3(512), 0, stream>>>(
      ctx, woT, b_o, out, nullptr, nullptr, nullptr, 32768, 768, 768);
}

// Round 5
// 628.248 us; speedup vs baseline: 1.3053x; 1.0409x over previous
//
#include <hip/hip_runtime.h>
#include <hip/hip_bf16.h>

typedef __attribute__((ext_vector_type(8))) short short8;
typedef __attribute__((ext_vector_type(4))) float floatx4;

#define NB 64
#define NS 512
#define ND 768
#define NH 12

__device__ __forceinline__ float bf2f(unsigned short u) {
  union { unsigned int i; float f; } v; v.i = ((unsigned int)u) << 16; return v.f;
}
__device__ __forceinline__ unsigned short f2bf(float f) {
  union { float f; unsigned int i; } v; v.f = f;
  unsigned int i = v.i;
  unsigned int r = i + 0x7fffu + ((i >> 16) & 1u);
  return (unsigned short)(r >> 16);
}

// async global->LDS, 16B per lane. LDS dest is wave-uniform base + lane*16.
__device__ __forceinline__ void gload_lds16(const unsigned short* g, unsigned short* l) {
  __builtin_amdgcn_global_load_lds(
      (const __attribute__((address_space(1))) unsigned int*)g,
      (__attribute__((address_space(3))) unsigned int*)l, 16, 0, 0);
}

#define WAITV(n) asm volatile("s_waitcnt vmcnt(" #n ")" ::: "memory")
#define PH_BAR() __builtin_amdgcn_s_barrier()
#define PH_LGKM0()                                        \
  {                                                       \
    asm volatile("s_waitcnt lgkmcnt(0)" ::: "memory");    \
    __builtin_amdgcn_sched_barrier(0);                    \
  }

// ------- fp32 -> bf16 convert: 4 elements/thread -------
__global__ void convert_k(const float* __restrict__ src, unsigned short* __restrict__ dst,
                          int n4) {
  int i = blockIdx.x * 256 + threadIdx.x;
  if (i >= n4) return;
  float4 v = ((const float4*)src)[i];
  ushort4 o;
  o.x = f2bf(v.x); o.y = f2bf(v.y); o.z = f2bf(v.z); o.w = f2bf(v.w);
  ((ushort4*)dst)[i] = o;
}

// ------- transpose + convert: in (R x C fp32) -> out (C x R bf16) ----
__global__ void transpose_cvt_k(const float* __restrict__ in, unsigned short* __restrict__ out,
                                int R, int C) {
  __shared__ unsigned short tile[32][33];
  int c0 = blockIdx.x * 32, r0 = blockIdx.y * 32;
  int tx = threadIdx.x, ty = threadIdx.y;
#pragma unroll
  for (int i = 0; i < 32; i += 8)
    tile[ty + i][tx] = f2bf(in[(r0 + ty + i) * C + c0 + tx]);
  __syncthreads();
#pragma unroll
  for (int i = 0; i < 32; i += 8) out[(c0 + ty + i) * R + r0 + tx] = tile[tx][ty + i];
}

// ---------------- GEMM: C = A(MxK bf16) * Bt(NxK bf16)^T + bias(fp32) ----------------
// 8-phase 256x256 tile, BK=64, 8 waves (2Mx4N), 4 A-half-slots + 4 B-half-slots (128 KiB),
// per-phase {ds_read || 1 half-tile stage || barrier || lgkm0 || setprio+16 MFMA || barrier},
// counted vmcnt(6) once per K-tile. XOR chunk swizzle both sides. XCD block swizzle.
// Stage ledger (tile t, phases p0..p3): A1(t+1)@p0, B0(t+2)@p2, {B1,A0}(t+2)@p3.
// Slot(half h of tile u) = (2u+h)&3; every overwrite >=2 barriers after last read.
// MODE 0: fp32 store. MODE 1: bf16 scatter Q/K (B,H,S,64) with fused RoPE, Vt (B,H,64,S).
template <int MODE>
__global__ __launch_bounds__(512, 2) void gemm_k(
    const unsigned short* __restrict__ A, const unsigned short* __restrict__ Bt,
    const float* __restrict__ bias, float* __restrict__ out,
    unsigned short* __restrict__ Qg, unsigned short* __restrict__ Kg,
    unsigned short* __restrict__ Vtg, int M, int N, int K) {
  __shared__ unsigned short ldsA[32768];  // 4 half-slots x (128 rows x 64 bf16)
  __shared__ unsigned short ldsB[32768];

  // XCD-aware swizzle (nwg % 8 == 0: QKV 1152, proj 384)
  int nbx = N >> 8;
  int nwg = (M >> 8) * nbx;
  int id = blockIdx.x;
  int q8 = nwg >> 3;
  int wg = (id & 7) * q8 + (id >> 3);
  int bx = wg % nbx, by = wg / nbx;
  int n0 = bx * 256, m0 = by * 256;

  int t = threadIdx.x;
  int w = t >> 6, lane = t & 63;
  int wm = (w >> 2) * 128, wn = (w & 3) * 64;  // wave owns 128x64 of C
  int lr = lane & 15, lq = lane >> 4;
  int wbase = w * 512;          // wave LDS stage base (shorts)
  int hA = w >> 2;              // wave's A-half
  int hB = (w & 3) >> 1;        // wave's B-half
  int rbin = (w & 1) * 64;      // row offset within B-half

  const size_t KK = (size_t)K;
  // stage source: thread t covers row t>>3, phys chunk t&7 holds global chunk (t&7)^((t>>3)&7)
  const unsigned short* gA = A + ((size_t)m0 + (t >> 3)) * KK + (((t & 7) ^ ((t >> 3) & 7)) * 8);
  const unsigned short* gB = Bt + ((size_t)n0 + (t >> 3)) * KK + (((t & 7) ^ ((t >> 3) & 7)) * 8);

  // frag-read chunk offsets (same involution): chunk (kk*4+lq) ^ (row&7), row&7 = lr&7
  int aoff0 = ((0 * 4 + lq) ^ (lr & 7)) * 8;
  int aoff1 = ((1 * 4 + lq) ^ (lr & 7)) * 8;

#define STAGE_A(tt, h)                                                     \
  {                                                                        \
    int sl_ = ((2 * (tt) + (h)) & 3) * 8192 + wbase;                       \
    const unsigned short* s_ = gA + (size_t)((h) * 128) * KK + (tt) * 64;  \
    gload_lds16(s_, &ldsA[sl_]);                                           \
    gload_lds16(s_ + 64 * KK, &ldsA[sl_ + 4096]);                          \
  }
#define STAGE_B(tt, h)                                                     \
  {                                                                        \
    int sl_ = ((2 * (tt) + (h)) & 3) * 8192 + wbase;                       \
    const unsigned short* s_ = gB + (size_t)((h) * 128) * KK + (tt) * 64;  \
    gload_lds16(s_, &ldsB[sl_]);                                           \
    gload_lds16(s_ + 64 * KK, &ldsB[sl_ + 4096]);                          \
  }

  floatx4 acc[8][4];
#pragma unroll
  for (int i = 0; i < 8; i++)
#pragma unroll
    for (int j = 0; j < 4; j++) acc[i][j] = (floatx4){0.f, 0.f, 0.f, 0.f};

  short8 fa[4][2];  // current mf-group frags
  short8 fb[4][2];  // all 4 nf frags (nf0-1 @p0, nf2-3 @p1)

#define DSRD_A(g)                                                                         \
  _Pragma("unroll") for (int i_ = 0; i_ < 4; i_++) {                                      \
    int ar_ = abase + (((g) * 4 + i_) * 16 + lr) * 64;                                    \
    fa[i_][0] = *(const short8*)&ldsA[ar_ + aoff0];                                       \
    fa[i_][1] = *(const short8*)&ldsA[ar_ + aoff1];                                       \
  }
#define DSRD_B(g)                                                                         \
  _Pragma("unroll") for (int i_ = 0; i_ < 2; i_++) {                                      \
    int br_ = bbase + (rbin + ((g) * 2 + i_) * 16 + lr) * 64;                             \
    fb[(g) * 2 + i_][0] = *(const short8*)&ldsB[br_ + aoff0];                             \
    fb[(g) * 2 + i_][1] = *(const short8*)&ldsB[br_ + aoff1];                             \
  }
#define MFMAQ(mg, ng)                                                                     \
  __builtin_amdgcn_s_setprio(1);                                                          \
  _Pragma("unroll") for (int i_ = 0; i_ < 4; i_++)                                        \
      _Pragma("unroll") for (int n_ = 0; n_ < 2; n_++)                                    \
          _Pragma("unroll") for (int k_ = 0; k_ < 2; k_++)                                \
              acc[(mg) * 4 + i_][(ng) * 2 + n_] = __builtin_amdgcn_mfma_f32_16x16x32_bf16( \
                  fa[i_][k_], fb[(ng) * 2 + n_][k_], acc[(mg) * 4 + i_][(ng) * 2 + n_],   \
                  0, 0, 0);                                                               \
  __builtin_amdgcn_s_setprio(0);

#define TILE(tt, doSA1, doSB0, doSB1A0, VM)              \
  {                                                      \
    int abase = ((2 * (tt) + hA) & 3) * 8192;            \
    int bbase = ((2 * (tt) + hB) & 3) * 8192;            \
    /* p0 */                                             \
    DSRD_A(0); DSRD_B(0);                                \
    if (doSA1) STAGE_A((tt) + 1, 1);                     \
    PH_BAR(); PH_LGKM0(); MFMAQ(0, 0); PH_BAR();         \
    /* p1 */                                             \
    DSRD_B(1);                                           \
    PH_BAR(); PH_LGKM0(); MFMAQ(0, 1); PH_BAR();         \
    /* p2 */                                             \
    DSRD_A(1);                                           \
    if (doSB0) STAGE_B((tt) + 2, 0);                     \
    PH_BAR(); PH_LGKM0(); MFMAQ(1, 0); PH_BAR();         \
    /* p3 */                                             \
    if (doSB1A0) { STAGE_B((tt) + 2, 1); STAGE_A((tt) + 2, 0); } \
    VM;                                                  \
    PH_BAR(); MFMAQ(1, 1); PH_BAR();                     \
  }

  const int NKT = K >> 6;  // 12 for K=768

  // prologue: tile0 (4 halves) + B0,B1,A0 of tile1 = 14 loads; certify tile0 (last 3 halves may fly)
  STAGE_A(0, 0); STAGE_B(0, 0); STAGE_A(0, 1); STAGE_B(0, 1);
  STAGE_B(1, 0); STAGE_B(1, 1); STAGE_A(1, 0);
  WAITV(6);
  PH_BAR();

  for (int tt = 0; tt < NKT - 2; ++tt) TILE(tt, 1, 1, 1, WAITV(6));
  TILE(NKT - 2, 1, 0, 0, WAITV(0));
  TILE(NKT - 1, 0, 0, 0, );

#undef TILE
#undef MFMAQ
#undef DSRD_A
#undef DSRD_B
#undef STAGE_A
#undef STAGE_B

  // ---------------- epilogue ----------------
  float bv[4];
#pragma unroll
  for (int nf = 0; nf < 4; nf++) bv[nf] = bias[n0 + wn + nf * 16 + lr];

  int part = 0, h = 0;
  float ivf0 = 0.f, ivf1 = 0.f;
  if (MODE == 1) {
    int nbase = n0 + wn;            // wave-uniform, 64-aligned => one head, one part
    part = nbase / ND;
    h = (nbase - part * ND) >> 6;
    ivf0 = __expf(-(float)lr * 0.28782313662425572f);         // invfreq(d=lr)
    ivf1 = __expf(-(float)(16 + lr) * 0.28782313662425572f);  // invfreq(d=16+lr)
  }

#pragma unroll
  for (int mf = 0; mf < 8; mf++) {
#pragma unroll
    for (int r = 0; r < 4; r++) {
      int m = m0 + wm + mf * 16 + lq * 4 + r;  // C/D: row=(lane>>4)*4+reg, col=lane&15
      float fo[4];
#pragma unroll
      for (int nf = 0; nf < 4; nf++) fo[nf] = acc[mf][nf][r] + bv[nf];
      if (MODE == 0) {
#pragma unroll
        for (int nf = 0; nf < 4; nf++)
          out[(size_t)m * N + (n0 + wn + nf * 16 + lr)] = fo[nf];
      } else {
        int b = m >> 9, s = m & 511;
        int bh = b * NH + h;
        if (part == 2) {
#pragma unroll
          for (int nf = 0; nf < 4; nf++)
            Vtg[((size_t)bh * 64 + nf * 16 + lr) * NS + s] = f2bf(fo[nf]);
        } else {
          // fused RoPE: head cols c = nf*16+lr; outputs (d, d+32) need inputs (2d, 2d+1).
          unsigned short* dst = (part ? Kg : Qg) + ((size_t)bh * NS + s) * 64;
          int sl0 = (lq << 4) | ((2 * lr) & 15);
          int sl1 = (lq << 4) | ((2 * lr + 1) & 15);
          float a_l = __shfl(fo[0], sl0), a_h = __shfl(fo[1], sl0);
          float b_l = __shfl(fo[0], sl1), b_h = __shfl(fo[1], sl1);
          float c_l = __shfl(fo[2], sl0), c_h = __shfl(fo[3], sl0);
          float d_l = __shfl(fo[2], sl1), d_h = __shfl(fo[3], sl1);
          bool lo = lr < 8;
          float Av = lo ? a_l : a_h, Bv = lo ? b_l : b_h;   // in(2lr), in(2lr+1)
          float Cv = lo ? c_l : c_h, Dv = lo ? d_l : d_h;   // in(32+2lr), in(33+2lr)
          float fs = (float)s;
          float sn0, cs0, sn1, cs1;
          __sincosf(fs * ivf0, &sn0, &cs0);
          __sincosf(fs * ivf1, &sn1, &cs1);
          dst[lr]      = f2bf(Av * cs0 - Bv * sn0);  // d = lr
          dst[16 + lr] = f2bf(Cv * cs1 - Dv * sn1);  // d = 16+lr
          dst[32 + lr] = f2bf(Av * sn0 + Bv * cs0);  // d+32
          dst[48 + lr] = f2bf(Cv * sn1 + Dv * cs1);  // d+32
        }
      }
    }
  }
}

// ---------------- flash attention: 1 WG = (b,h) x 64 q-rows, LDS-staged K/V ----------------
// Grid = (bh, qt): linear id = bh + qt*768, 768 % 8 == 0 -> all qt-blocks of one bh land on
// the SAME XCD, so K/V is HBM-fetched once and L2-served for the other 7 blocks.
__global__ __launch_bounds__(256) void attn_k(
    const unsigned short* __restrict__ Qg, const unsigned short* __restrict__ Kg,
    const unsigned short* __restrict__ Vtg, unsigned short* __restrict__ ctx) {
  __shared__ unsigned short Ks[64 * 72];
  __shared__ unsigned short Vs[64 * 72];
  __shared__ unsigned short Ps[4][16 * 72];
  int bh = blockIdx.x, qt = blockIdx.y;
  int t = threadIdx.x, w = t >> 6, lane = t & 63;
  int lr = lane & 15, lq = lane >> 4;
  int q0 = qt * 64 + w * 16;
  const unsigned short* Qb = Qg + (bh * NS + q0) * 64;
  short8 qf0 = *(const short8*)&Qb[lr * 64 + lq * 8];
  short8 qf1 = *(const short8*)&Qb[lr * 64 + 32 + lq * 8];
  floatx4 o[4];
#pragma unroll
  for (int ft = 0; ft < 4; ft++) o[ft] = (floatx4){0.f, 0.f, 0.f, 0.f};
  float m_[4] = {-1e30f, -1e30f, -1e30f, -1e30f};
  float l_[4] = {0.f, 0.f, 0.f, 0.f};
  int srow = t >> 2, scc = t & 3;
  const unsigned short* Kb = Kg + bh * NS * 64;
  const unsigned short* Vb = Vtg + bh * 64 * NS;

  for (int kt = 0; kt < 8; kt++) {
    __syncthreads();
    *(short8*)&Ks[srow * 72 + scc * 8]      = *(const short8*)&Kb[(kt * 64 + srow) * 64 + scc * 8];
    *(short8*)&Ks[srow * 72 + 32 + scc * 8] = *(const short8*)&Kb[(kt * 64 + srow) * 64 + 32 + scc * 8];
    *(short8*)&Vs[srow * 72 + scc * 8]      = *(const short8*)&Vb[srow * NS + kt * 64 + scc * 8];
    *(short8*)&Vs[srow * 72 + 32 + scc * 8] = *(const short8*)&Vb[srow * NS + kt * 64 + 32 + scc * 8];
    __syncthreads();

    floatx4 sf[4];
#pragma unroll
    for (int nt = 0; nt < 4; nt++) sf[nt] = (floatx4){0.f, 0.f, 0.f, 0.f};
#pragma unroll
    for (int nt = 0; nt < 4; nt++) {
      short8 k0 = *(const short8*)&Ks[(nt * 16 + lr) * 72 + lq * 8];
      short8 k1 = *(const short8*)&Ks[(nt * 16 + lr) * 72 + 32 + lq * 8];
      sf[nt] = __builtin_amdgcn_mfma_f32_16x16x32_bf16(qf0, k0, sf[nt], 0, 0, 0);
      sf[nt] = __builtin_amdgcn_mfma_f32_16x16x32_bf16(qf1, k1, sf[nt], 0, 0, 0);
    }
    float alpha[4];
#pragma unroll
    for (int r = 0; r < 4; r++) {
      float v = fmaxf(fmaxf(sf[0][r], sf[1][r]), fmaxf(sf[2][r], sf[3][r])) * 0.125f;
      v = fmaxf(v, __shfl_xor(v, 1));
      v = fmaxf(v, __shfl_xor(v, 2));
      v = fmaxf(v, __shfl_xor(v, 4));
      v = fmaxf(v, __shfl_xor(v, 8));
      float mn = fmaxf(m_[r], v);
      alpha[r] = __expf(m_[r] - mn);
      m_[r] = mn;
    }
    float rsum[4] = {0.f, 0.f, 0.f, 0.f};
#pragma unroll
    for (int nt = 0; nt < 4; nt++)
#pragma unroll
      for (int r = 0; r < 4; r++) {
        float pv = __expf(sf[nt][r] * 0.125f - m_[r]);
        rsum[r] += pv;
        Ps[w][(lq * 4 + r) * 72 + nt * 16 + lr] = f2bf(pv);
      }
#pragma unroll
    for (int r = 0; r < 4; r++) {
      float v = rsum[r];
      v += __shfl_xor(v, 1);
      v += __shfl_xor(v, 2);
      v += __shfl_xor(v, 4);
      v += __shfl_xor(v, 8);
      l_[r] = l_[r] * alpha[r] + v;
    }
#pragma unroll
    for (int ft = 0; ft < 4; ft++)
#pragma unroll
      for (int r = 0; r < 4; r++) o[ft][r] *= alpha[r];
#pragma unroll
    for (int ks = 0; ks < 2; ks++) {
      short8 pf = *(const short8*)&Ps[w][lr * 72 + ks * 32 + lq * 8];
#pragma unroll
      for (int ft = 0; ft < 4; ft++) {
        short8 vf = *(const short8*)&Vs[(ft * 16 + lr) * 72 + ks * 32 + lq * 8];
        o[ft] = __builtin_amdgcn_mfma_f32_16x16x32_bf16(pf, vf, o[ft], 0, 0, 0);
      }
    }
  }
  int b = bh / NH, h = bh - (bh / NH) * NH;
#pragma unroll
  for (int r = 0; r < 4; r++) {
    float inv = 1.f / l_[r];
#pragma unroll
    for (int ft = 0; ft < 4; ft++)
      ctx[(b * NS + q0 + lq * 4 + r) * ND + h * 64 + ft * 16 + lr] = f2bf(o[ft][r] * inv);
  }
}

extern "C" void kernel_launch(void* const* d_in, const int* in_sizes, int n_in,
                              void* d_out, int out_size, void* d_ws, size_t ws_size,
                              hipStream_t stream) {
  const float* x     = (const float*)d_in[0];   // fp32 (confirmed: bf16 read -> NaN)
  const float* w_qkv = (const float*)d_in[1];   // (768, 2304) fp32
  const float* b_qkv = (const float*)d_in[2];
  const float* w_o   = (const float*)d_in[3];   // (768, 768) fp32
  const float* b_o   = (const float*)d_in[4];
  float* out = (float*)d_out;                   // fp32: reference output dtype

  char* ws = (char*)d_ws;
  unsigned short* xb    = (unsigned short*)(ws);              // x bf16; reused as ctx
  unsigned short* wqkvT = (unsigned short*)(ws + 50331648);   // 2304x768 bf16
  unsigned short* woT   = (unsigned short*)(ws + 53870592);   // 768x768 bf16
  unsigned short* Qg    = (unsigned short*)(ws + 55050240);   // (B,H,S,64) bf16, roped
  unsigned short* Kg    = (unsigned short*)(ws + 105381888);  // roped
  unsigned short* Vtg   = (unsigned short*)(ws + 155713536);
  unsigned short* ctx   = xb;  // x dead after QKV GEMM

  transpose_cvt_k<<<dim3(2304 / 32, 768 / 32), dim3(32, 8), 0, stream>>>(w_qkv, wqkvT, 768, 2304);
  transpose_cvt_k<<<dim3(768 / 32, 768 / 32), dim3(32, 8), 0, stream>>>(w_o, woT, 768, 768);
  convert_k<<<24576, 256, 0, stream>>>(x, xb, 6291456);
  gemm_k<1><<<dim3((32768 / 256) * (2304 / 256)), dim3(512), 0, stream>>>(
      xb, wqkvT, b_qkv, nullptr, Qg, Kg, Vtg, 32768, 2304, 768);
  attn_k<<<dim3(NB * NH, NS / 64), dim3(256), 0, stream>>>(Qg, Kg, Vtg, ctx);
  gemm_k<0><<<dim3((32768 / 256) * (768 / 256)), dim3(512), 0, stream>>>(
      ctx, woT, b_o, out, nullptr, nullptr, nullptr, 32768, 768, 768);
}

// Round 6
// 621.803 us; speedup vs baseline: 1.3188x; 1.0104x over previous
//
#include <hip/hip_runtime.h>
#include <hip/hip_bf16.h>

typedef __attribute__((ext_vector_type(8))) short short8;
typedef __attribute__((ext_vector_type(4))) float floatx4;

#define NB 64
#define NS 512
#define ND 768
#define NH 12

__device__ __forceinline__ float bf2f(unsigned short u) {
  union { unsigned int i; float f; } v; v.i = ((unsigned int)u) << 16; return v.f;
}
__device__ __forceinline__ unsigned short f2bf(float f) {
  union { float f; unsigned int i; } v; v.f = f;
  unsigned int i = v.i;
  unsigned int r = i + 0x7fffu + ((i >> 16) & 1u);
  return (unsigned short)(r >> 16);
}

// async global->LDS, 16B per lane. LDS dest is wave-uniform base + lane*16.
__device__ __forceinline__ void gload_lds16(const unsigned short* g, unsigned short* l) {
  __builtin_amdgcn_global_load_lds(
      (const __attribute__((address_space(1))) unsigned int*)g,
      (__attribute__((address_space(3))) unsigned int*)l, 16, 0, 0);
}

#define WAITV(n) asm volatile("s_waitcnt vmcnt(" #n ")" ::: "memory")
#define PH_BAR() __builtin_amdgcn_s_barrier()
#define PH_LGKM0()                                        \
  {                                                       \
    asm volatile("s_waitcnt lgkmcnt(0)" ::: "memory");    \
    __builtin_amdgcn_sched_barrier(0);                    \
  }

// ------- fp32 -> bf16 convert: 4 elements/thread -------
__global__ void convert_k(const float* __restrict__ src, unsigned short* __restrict__ dst,
                          int n4) {
  int i = blockIdx.x * 256 + threadIdx.x;
  if (i >= n4) return;
  float4 v = ((const float4*)src)[i];
  ushort4 o;
  o.x = f2bf(v.x); o.y = f2bf(v.y); o.z = f2bf(v.z); o.w = f2bf(v.w);
  ((ushort4*)dst)[i] = o;
}

// ------- transpose + convert: in (R x C fp32) -> out (C x R bf16) ----
__global__ void transpose_cvt_k(const float* __restrict__ in, unsigned short* __restrict__ out,
                                int R, int C) {
  __shared__ unsigned short tile[32][33];
  int c0 = blockIdx.x * 32, r0 = blockIdx.y * 32;
  int tx = threadIdx.x, ty = threadIdx.y;
#pragma unroll
  for (int i = 0; i < 32; i += 8)
    tile[ty + i][tx] = f2bf(in[(r0 + ty + i) * C + c0 + tx]);
  __syncthreads();
#pragma unroll
  for (int i = 0; i < 32; i += 8) out[(c0 + ty + i) * R + r0 + tx] = tile[tx][ty + i];
}

// ---------------- GEMM: C = A(MxK bf16) * Bt(NxK bf16)^T + bias(fp32) ----------------
// 8-phase 256x256 tile, BK=64, 8 waves (2Mx4N), 4 A-half-slots + 4 B-half-slots (128 KiB).
// R6: ds_reads software-pipelined ONE PHASE AHEAD of their consuming MFMA (register
// sets fa0/fa1/fb0/fb1), so the LDS backlog drains under the current phase's MFMA
// instead of serializing via {barrier; lgkmcnt0; MFMA}. Only p0 keeps a read convoy
// (cross-tile reads must follow the vmcnt(6)+barrier certification).
// Stage ledger (tile t): A1(t+1)@S0, B0(t+2)@S2, {B1,A0}(t+2)@S3; slot(half h of u)=(2u+h)&3.
// MODE 0: fp32 store. MODE 1: bf16 scatter Q/K (B,H,S,64) with fused RoPE, Vt (B,H,64,S).
template <int MODE>
__global__ __launch_bounds__(512, 2) void gemm_k(
    const unsigned short* __restrict__ A, const unsigned short* __restrict__ Bt,
    const float* __restrict__ bias, float* __restrict__ out,
    unsigned short* __restrict__ Qg, unsigned short* __restrict__ Kg,
    unsigned short* __restrict__ Vtg, int M, int N, int K) {
  __shared__ unsigned short ldsA[32768];  // 4 half-slots x (128 rows x 64 bf16)
  __shared__ unsigned short ldsB[32768];

  // XCD-aware swizzle (nwg % 8 == 0: QKV 1152, proj 384)
  int nbx = N >> 8;
  int nwg = (M >> 8) * nbx;
  int id = blockIdx.x;
  int q8 = nwg >> 3;
  int wg = (id & 7) * q8 + (id >> 3);
  int bx = wg % nbx, by = wg / nbx;
  int n0 = bx * 256, m0 = by * 256;

  int t = threadIdx.x;
  int w = t >> 6, lane = t & 63;
  int wm = (w >> 2) * 128, wn = (w & 3) * 64;  // wave owns 128x64 of C
  int lr = lane & 15, lq = lane >> 4;
  int wbase = w * 512;          // wave LDS stage base (shorts)
  int hA = w >> 2;              // wave's A-half
  int hB = (w & 3) >> 1;        // wave's B-half
  int rbin = (w & 1) * 64;      // row offset within B-half

  const size_t KK = (size_t)K;
  // stage source: thread t covers row t>>3, phys chunk t&7 holds global chunk (t&7)^((t>>3)&7)
  const unsigned short* gA = A + ((size_t)m0 + (t >> 3)) * KK + (((t & 7) ^ ((t >> 3) & 7)) * 8);
  const unsigned short* gB = Bt + ((size_t)n0 + (t >> 3)) * KK + (((t & 7) ^ ((t >> 3) & 7)) * 8);

  // frag-read chunk offsets (same involution): chunk (kk*4+lq) ^ (row&7), row&7 = lr&7
  int aoff0 = ((0 * 4 + lq) ^ (lr & 7)) * 8;
  int aoff1 = ((1 * 4 + lq) ^ (lr & 7)) * 8;

#define STAGE_A(tt, h)                                                     \
  {                                                                        \
    int sl_ = ((2 * (tt) + (h)) & 3) * 8192 + wbase;                       \
    const unsigned short* s_ = gA + (size_t)((h) * 128) * KK + (tt) * 64;  \
    gload_lds16(s_, &ldsA[sl_]);                                           \
    gload_lds16(s_ + 64 * KK, &ldsA[sl_ + 4096]);                          \
  }
#define STAGE_B(tt, h)                                                     \
  {                                                                        \
    int sl_ = ((2 * (tt) + (h)) & 3) * 8192 + wbase;                       \
    const unsigned short* s_ = gB + (size_t)((h) * 128) * KK + (tt) * 64;  \
    gload_lds16(s_, &ldsB[sl_]);                                           \
    gload_lds16(s_ + 64 * KK, &ldsB[sl_ + 4096]);                          \
  }

  floatx4 acc[8][4];
#pragma unroll
  for (int i = 0; i < 8; i++)
#pragma unroll
    for (int j = 0; j < 4; j++) acc[i][j] = (floatx4){0.f, 0.f, 0.f, 0.f};

  short8 fa0[4][2], fa1[4][2];  // A fragments, mf-groups 0 (rows 0-63) and 1 (rows 64-127)
  short8 fb0[2][2], fb1[2][2];  // B fragments, nf-groups 0 (nf0-1) and 1 (nf2-3)

#define DSRD_A(dst, g)                                                                    \
  _Pragma("unroll") for (int i_ = 0; i_ < 4; i_++) {                                      \
    int ar_ = abase + (((g) * 4 + i_) * 16 + lr) * 64;                                    \
    dst[i_][0] = *(const short8*)&ldsA[ar_ + aoff0];                                      \
    dst[i_][1] = *(const short8*)&ldsA[ar_ + aoff1];                                      \
  }
#define DSRD_B(dst, g)                                                                    \
  _Pragma("unroll") for (int i_ = 0; i_ < 2; i_++) {                                      \
    int br_ = bbase + (rbin + ((g) * 2 + i_) * 16 + lr) * 64;                             \
    dst[i_][0] = *(const short8*)&ldsB[br_ + aoff0];                                      \
    dst[i_][1] = *(const short8*)&ldsB[br_ + aoff1];                                      \
  }
#define MFMAQ2(A_, B_, mg, ng)                                                            \
  __builtin_amdgcn_s_setprio(1);                                                          \
  _Pragma("unroll") for (int i_ = 0; i_ < 4; i_++)                                        \
      _Pragma("unroll") for (int n_ = 0; n_ < 2; n_++)                                    \
          _Pragma("unroll") for (int k_ = 0; k_ < 2; k_++)                                \
              acc[(mg) * 4 + i_][(ng) * 2 + n_] =                                         \
                  __builtin_amdgcn_mfma_f32_16x16x32_bf16(                                \
                      A_[i_][k_], B_[n_][k_], acc[(mg) * 4 + i_][(ng) * 2 + n_], 0, 0, 0); \
  __builtin_amdgcn_s_setprio(0);

  // Per K-tile: M0{rd FA0,FB0; wait; MFMA00; rd FB1} |S0 stage A1(t+1)| M1{wait; MFMA01;
  // rd FA1} | M2{wait; MFMA10} |S2 stage B0(t+2)| M3{MFMA11} |S3 stage B1,A0(t+2); vmcnt|
#define TILE(tt, doSA1, doSB0, doSB1A0, VM)                      \
  {                                                              \
    int abase = ((2 * (tt) + hA) & 3) * 8192;                    \
    int bbase = ((2 * (tt) + hB) & 3) * 8192;                    \
    /* M0 */                                                     \
    DSRD_A(fa0, 0); DSRD_B(fb0, 0);                              \
    PH_LGKM0(); MFMAQ2(fa0, fb0, 0, 0); DSRD_B(fb1, 1);          \
    PH_BAR();                                                    \
    /* S0 */                                                     \
    if (doSA1) STAGE_A((tt) + 1, 1);                             \
    PH_BAR();                                                    \
    /* M1 */                                                     \
    PH_LGKM0(); MFMAQ2(fa0, fb1, 0, 1); DSRD_A(fa1, 1);          \
    PH_BAR();                                                    \
    /* M2 */                                                     \
    PH_LGKM0(); MFMAQ2(fa1, fb0, 1, 0);                          \
    PH_BAR();                                                    \
    /* S2 */                                                     \
    if (doSB0) STAGE_B((tt) + 2, 0);                             \
    PH_BAR();                                                    \
    /* M3: operands certified at M1/M2 waits */                  \
    MFMAQ2(fa1, fb1, 1, 1);                                      \
    PH_BAR();                                                    \
    /* S3 */                                                     \
    if (doSB1A0) { STAGE_B((tt) + 2, 1); STAGE_A((tt) + 2, 0); } \
    VM;                                                          \
    PH_BAR();                                                    \
  }

  const int NKT = K >> 6;  // 12 for K=768

  // prologue: tile0 (4 halves) + B0,B1,A0 of tile1 = 14 loads; certify tile0
  STAGE_A(0, 0); STAGE_B(0, 0); STAGE_A(0, 1); STAGE_B(0, 1);
  STAGE_B(1, 0); STAGE_B(1, 1); STAGE_A(1, 0);
  WAITV(6);
  PH_BAR();

  for (int tt = 0; tt < NKT - 2; ++tt) TILE(tt, 1, 1, 1, WAITV(6));
  TILE(NKT - 2, 1, 0, 0, WAITV(0));
  TILE(NKT - 1, 0, 0, 0, );

#undef TILE
#undef MFMAQ2
#undef DSRD_A
#undef DSRD_B
#undef STAGE_A
#undef STAGE_B

  // ---------------- epilogue ----------------
  float bv[4];
#pragma unroll
  for (int nf = 0; nf < 4; nf++) bv[nf] = bias[n0 + wn + nf * 16 + lr];

  int part = 0, h = 0;
  float ivf0 = 0.f, ivf1 = 0.f;
  if (MODE == 1) {
    int nbase = n0 + wn;            // wave-uniform, 64-aligned => one head, one part
    part = nbase / ND;
    h = (nbase - part * ND) >> 6;
    ivf0 = __expf(-(float)lr * 0.28782313662425572f);         // invfreq(d=lr)
    ivf1 = __expf(-(float)(16 + lr) * 0.28782313662425572f);  // invfreq(d=16+lr)
  }

#pragma unroll
  for (int mf = 0; mf < 8; mf++) {
#pragma unroll
    for (int r = 0; r < 4; r++) {
      int m = m0 + wm + mf * 16 + lq * 4 + r;  // C/D: row=(lane>>4)*4+reg, col=lane&15
      float fo[4];
#pragma unroll
      for (int nf = 0; nf < 4; nf++) fo[nf] = acc[mf][nf][r] + bv[nf];
      if (MODE == 0) {
#pragma unroll
        for (int nf = 0; nf < 4; nf++)
          out[(size_t)m * N + (n0 + wn + nf * 16 + lr)] = fo[nf];
      } else {
        int b = m >> 9, s = m & 511;
        int bh = b * NH + h;
        if (part == 2) {
#pragma unroll
          for (int nf = 0; nf < 4; nf++)
            Vtg[((size_t)bh * 64 + nf * 16 + lr) * NS + s] = f2bf(fo[nf]);
        } else {
          // fused RoPE: head cols c = nf*16+lr; outputs (d, d+32) need inputs (2d, 2d+1).
          unsigned short* dst = (part ? Kg : Qg) + ((size_t)bh * NS + s) * 64;
          int sl0 = (lq << 4) | ((2 * lr) & 15);
          int sl1 = (lq << 4) | ((2 * lr + 1) & 15);
          float a_l = __shfl(fo[0], sl0), a_h = __shfl(fo[1], sl0);
          float b_l = __shfl(fo[0], sl1), b_h = __shfl(fo[1], sl1);
          float c_l = __shfl(fo[2], sl0), c_h = __shfl(fo[3], sl0);
          float d_l = __shfl(fo[2], sl1), d_h = __shfl(fo[3], sl1);
          bool lo = lr < 8;
          float Av = lo ? a_l : a_h, Bv = lo ? b_l : b_h;   // in(2lr), in(2lr+1)
          float Cv = lo ? c_l : c_h, Dv = lo ? d_l : d_h;   // in(32+2lr), in(33+2lr)
          float fs = (float)s;
          float sn0, cs0, sn1, cs1;
          __sincosf(fs * ivf0, &sn0, &cs0);
          __sincosf(fs * ivf1, &sn1, &cs1);
          dst[lr]      = f2bf(Av * cs0 - Bv * sn0);  // d = lr
          dst[16 + lr] = f2bf(Cv * cs1 - Dv * sn1);  // d = 16+lr
          dst[32 + lr] = f2bf(Av * sn0 + Bv * cs0);  // d+32
          dst[48 + lr] = f2bf(Cv * sn1 + Dv * cs1);  // d+32
        }
      }
    }
  }
}

// ---------------- flash attention: 1 WG = (b,h) x 64 q-rows, LDS-staged K/V ----------------
// Grid = (bh, qt): linear id = bh + qt*768, 768 % 8 == 0 -> all qt-blocks of one bh land on
// the SAME XCD, so K/V is HBM-fetched once and L2-served for the other 7 blocks.
__global__ __launch_bounds__(256) void attn_k(
    const unsigned short* __restrict__ Qg, const unsigned short* __restrict__ Kg,
    const unsigned short* __restrict__ Vtg, unsigned short* __restrict__ ctx) {
  __shared__ unsigned short Ks[64 * 72];
  __shared__ unsigned short Vs[64 * 72];
  __shared__ unsigned short Ps[4][16 * 72];
  int bh = blockIdx.x, qt = blockIdx.y;
  int t = threadIdx.x, w = t >> 6, lane = t & 63;
  int lr = lane & 15, lq = lane >> 4;
  int q0 = qt * 64 + w * 16;
  const unsigned short* Qb = Qg + (bh * NS + q0) * 64;
  short8 qf0 = *(const short8*)&Qb[lr * 64 + lq * 8];
  short8 qf1 = *(const short8*)&Qb[lr * 64 + 32 + lq * 8];
  floatx4 o[4];
#pragma unroll
  for (int ft = 0; ft < 4; ft++) o[ft] = (floatx4){0.f, 0.f, 0.f, 0.f};
  float m_[4] = {-1e30f, -1e30f, -1e30f, -1e30f};
  float l_[4] = {0.f, 0.f, 0.f, 0.f};
  int srow = t >> 2, scc = t & 3;
  const unsigned short* Kb = Kg + bh * NS * 64;
  const unsigned short* Vb = Vtg + bh * 64 * NS;

  for (int kt = 0; kt < 8; kt++) {
    __syncthreads();
    *(short8*)&Ks[srow * 72 + scc * 8]      = *(const short8*)&Kb[(kt * 64 + srow) * 64 + scc * 8];
    *(short8*)&Ks[srow * 72 + 32 + scc * 8] = *(const short8*)&Kb[(kt * 64 + srow) * 64 + 32 + scc * 8];
    *(short8*)&Vs[srow * 72 + scc * 8]      = *(const short8*)&Vb[srow * NS + kt * 64 + scc * 8];
    *(short8*)&Vs[srow * 72 + 32 + scc * 8] = *(const short8*)&Vb[srow * NS + kt * 64 + 32 + scc * 8];
    __syncthreads();

    floatx4 sf[4];
#pragma unroll
    for (int nt = 0; nt < 4; nt++) sf[nt] = (floatx4){0.f, 0.f, 0.f, 0.f};
#pragma unroll
    for (int nt = 0; nt < 4; nt++) {
      short8 k0 = *(const short8*)&Ks[(nt * 16 + lr) * 72 + lq * 8];
      short8 k1 = *(const short8*)&Ks[(nt * 16 + lr) * 72 + 32 + lq * 8];
      sf[nt] = __builtin_amdgcn_mfma_f32_16x16x32_bf16(qf0, k0, sf[nt], 0, 0, 0);
      sf[nt] = __builtin_amdgcn_mfma_f32_16x16x32_bf16(qf1, k1, sf[nt], 0, 0, 0);
    }
    float alpha[4];
#pragma unroll
    for (int r = 0; r < 4; r++) {
      float v = fmaxf(fmaxf(sf[0][r], sf[1][r]), fmaxf(sf[2][r], sf[3][r])) * 0.125f;
      v = fmaxf(v, __shfl_xor(v, 1));
      v = fmaxf(v, __shfl_xor(v, 2));
      v = fmaxf(v, __shfl_xor(v, 4));
      v = fmaxf(v, __shfl_xor(v, 8));
      float mn = fmaxf(m_[r], v);
      alpha[r] = __expf(m_[r] - mn);
      m_[r] = mn;
    }
    float rsum[4] = {0.f, 0.f, 0.f, 0.f};
#pragma unroll
    for (int nt = 0; nt < 4; nt++)
#pragma unroll
      for (int r = 0; r < 4; r++) {
        float pv = __expf(sf[nt][r] * 0.125f - m_[r]);
        rsum[r] += pv;
        Ps[w][(lq * 4 + r) * 72 + nt * 16 + lr] = f2bf(pv);
      }
#pragma unroll
    for (int r = 0; r < 4; r++) {
      float v = rsum[r];
      v += __shfl_xor(v, 1);
      v += __shfl_xor(v, 2);
      v += __shfl_xor(v, 4);
      v += __shfl_xor(v, 8);
      l_[r] = l_[r] * alpha[r] + v;
    }
#pragma unroll
    for (int ft = 0; ft < 4; ft++)
#pragma unroll
      for (int r = 0; r < 4; r++) o[ft][r] *= alpha[r];
#pragma unroll
    for (int ks = 0; ks < 2; ks++) {
      short8 pf = *(const short8*)&Ps[w][lr * 72 + ks * 32 + lq * 8];
#pragma unroll
      for (int ft = 0; ft < 4; ft++) {
        short8 vf = *(const short8*)&Vs[(ft * 16 + lr) * 72 + ks * 32 + lq * 8];
        o[ft] = __builtin_amdgcn_mfma_f32_16x16x32_bf16(pf, vf, o[ft], 0, 0, 0);
      }
    }
  }
  int b = bh / NH, h = bh - (bh / NH) * NH;
#pragma unroll
  for (int r = 0; r < 4; r++) {
    float inv = 1.f / l_[r];
#pragma unroll
    for (int ft = 0; ft < 4; ft++)
      ctx[(b * NS + q0 + lq * 4 + r) * ND + h * 64 + ft * 16 + lr] = f2bf(o[ft][r] * inv);
  }
}

extern "C" void kernel_launch(void* const* d_in, const int* in_sizes, int n_in,
                              void* d_out, int out_size, void* d_ws, size_t ws_size,
                              hipStream_t stream) {
  const float* x     = (const float*)d_in[0];   // fp32 (confirmed: bf16 read -> NaN)
  const float* w_qkv = (const float*)d_in[1];   // (768, 2304) fp32
  const float* b_qkv = (const float*)d_in[2];
  const float* w_o   = (const float*)d_in[3];   // (768, 768) fp32
  const float* b_o   = (const float*)d_in[4];
  float* out = (float*)d_out;                   // fp32: reference output dtype

  char* ws = (char*)d_ws;
  unsigned short* xb    = (unsigned short*)(ws);              // x bf16; reused as ctx
  unsigned short* wqkvT = (unsigned short*)(ws + 50331648);   // 2304x768 bf16
  unsigned short* woT   = (unsigned short*)(ws + 53870592);   // 768x768 bf16
  unsigned short* Qg    = (unsigned short*)(ws + 55050240);   // (B,H,S,64) bf16, roped
  unsigned short* Kg    = (unsigned short*)(ws + 105381888);  // roped
  unsigned short* Vtg   = (unsigned short*)(ws + 155713536);
  unsigned short* ctx   = xb;  // x dead after QKV GEMM

  transpose_cvt_k<<<dim3(2304 / 32, 768 / 32), dim3(32, 8), 0, stream>>>(w_qkv, wqkvT, 768, 2304);
  transpose_cvt_k<<<dim3(768 / 32, 768 / 32), dim3(32, 8), 0, stream>>>(w_o, woT, 768, 768);
  convert_k<<<24576, 256, 0, stream>>>(x, xb, 6291456);
  gemm_k<1><<<dim3((32768 / 256) * (2304 / 256)), dim3(512), 0, stream>>>(
      xb, wqkvT, b_qkv, nullptr, Qg, Kg, Vtg, 32768, 2304, 768);
  attn_k<<<dim3(NB * NH, NS / 64), dim3(256), 0, stream>>>(Qg, Kg, Vtg, ctx);
  gemm_k<0><<<dim3((32768 / 256) * (768 / 256)), dim3(512), 0, stream>>>(
      ctx, woT, b_o, out, nullptr, nullptr, nullptr, 32768, 768, 768);
}

// Round 7
// 591.646 us; speedup vs baseline: 1.3860x; 1.0510x over previous
//
#include <hip/hip_runtime.h>
#include <hip/hip_bf16.h>

typedef __attribute__((ext_vector_type(8))) short short8;
typedef __attribute__((ext_vector_type(4))) float floatx4;

#define NB 64
#define NS 512
#define ND 768
#define NH 12

__device__ __forceinline__ float bf2f(unsigned short u) {
  union { unsigned int i; float f; } v; v.i = ((unsigned int)u) << 16; return v.f;
}
__device__ __forceinline__ unsigned short f2bf(float f) {
  union { float f; unsigned int i; } v; v.f = f;
  unsigned int i = v.i;
  unsigned int r = i + 0x7fffu + ((i >> 16) & 1u);
  return (unsigned short)(r >> 16);
}

// async global->LDS, 16B per lane. LDS dest is wave-uniform base + lane*16.
__device__ __forceinline__ void gload_lds16(const unsigned short* g, unsigned short* l) {
  __builtin_amdgcn_global_load_lds(
      (const __attribute__((address_space(1))) unsigned int*)g,
      (__attribute__((address_space(3))) unsigned int*)l, 16, 0, 0);
}

#define WAITV(n) asm volatile("s_waitcnt vmcnt(" #n ")" ::: "memory")
#define PH_BAR() __builtin_amdgcn_s_barrier()
#define PH_LGKM0()                                        \
  {                                                       \
    asm volatile("s_waitcnt lgkmcnt(0)" ::: "memory");    \
    __builtin_amdgcn_sched_barrier(0);                    \
  }

// ------- fp32 -> bf16 convert: 4 elements/thread -------
__global__ void convert_k(const float* __restrict__ src, unsigned short* __restrict__ dst,
                          int n4) {
  int i = blockIdx.x * 256 + threadIdx.x;
  if (i >= n4) return;
  float4 v = ((const float4*)src)[i];
  ushort4 o;
  o.x = f2bf(v.x); o.y = f2bf(v.y); o.z = f2bf(v.z); o.w = f2bf(v.w);
  ((ushort4*)dst)[i] = o;
}

// ------- transpose + convert: in (R x C fp32) -> out (C x R bf16) ----
__global__ void transpose_cvt_k(const float* __restrict__ in, unsigned short* __restrict__ out,
                                int R, int C) {
  __shared__ unsigned short tile[32][33];
  int c0 = blockIdx.x * 32, r0 = blockIdx.y * 32;
  int tx = threadIdx.x, ty = threadIdx.y;
#pragma unroll
  for (int i = 0; i < 32; i += 8)
    tile[ty + i][tx] = f2bf(in[(r0 + ty + i) * C + c0 + tx]);
  __syncthreads();
#pragma unroll
  for (int i = 0; i < 32; i += 8) out[(c0 + ty + i) * R + r0 + tx] = tile[tx][ty + i];
}

// ---------------- GEMM: C = A(MxK bf16) * Bt(NxK bf16)^T + bias(fp32) ----------------
// 8-phase 256x256 tile, BK=64, 8 waves (2Mx4N), 4 A-half-slots + 4 B-half-slots (128 KiB).
// ds_reads software-pipelined one phase ahead of their consuming MFMA.
// MODE 0: fp32 store. MODE 1: bf16 scatter Q/K (B,H,S,64) with fused RoPE, Vt (B,H,64,S).
template <int MODE>
__global__ __launch_bounds__(512, 2) void gemm_k(
    const unsigned short* __restrict__ A, const unsigned short* __restrict__ Bt,
    const float* __restrict__ bias, float* __restrict__ out,
    unsigned short* __restrict__ Qg, unsigned short* __restrict__ Kg,
    unsigned short* __restrict__ Vtg, int M, int N, int K) {
  __shared__ unsigned short ldsA[32768];  // 4 half-slots x (128 rows x 64 bf16)
  __shared__ unsigned short ldsB[32768];

  // XCD-aware swizzle (nwg % 8 == 0: QKV 1152, proj 384)
  int nbx = N >> 8;
  int nwg = (M >> 8) * nbx;
  int id = blockIdx.x;
  int q8 = nwg >> 3;
  int wg = (id & 7) * q8 + (id >> 3);
  int bx = wg % nbx, by = wg / nbx;
  int n0 = bx * 256, m0 = by * 256;

  int t = threadIdx.x;
  int w = t >> 6, lane = t & 63;
  int wm = (w >> 2) * 128, wn = (w & 3) * 64;  // wave owns 128x64 of C
  int lr = lane & 15, lq = lane >> 4;
  int wbase = w * 512;          // wave LDS stage base (shorts)
  int hA = w >> 2;              // wave's A-half
  int hB = (w & 3) >> 1;        // wave's B-half
  int rbin = (w & 1) * 64;      // row offset within B-half

  const size_t KK = (size_t)K;
  // stage source: thread t covers row t>>3, phys chunk t&7 holds global chunk (t&7)^((t>>3)&7)
  const unsigned short* gA = A + ((size_t)m0 + (t >> 3)) * KK + (((t & 7) ^ ((t >> 3) & 7)) * 8);
  const unsigned short* gB = Bt + ((size_t)n0 + (t >> 3)) * KK + (((t & 7) ^ ((t >> 3) & 7)) * 8);

  // frag-read chunk offsets (same involution): chunk (kk*4+lq) ^ (row&7), row&7 = lr&7
  int aoff0 = ((0 * 4 + lq) ^ (lr & 7)) * 8;
  int aoff1 = ((1 * 4 + lq) ^ (lr & 7)) * 8;

#define STAGE_A(tt, h)                                                     \
  {                                                                        \
    int sl_ = ((2 * (tt) + (h)) & 3) * 8192 + wbase;                       \
    const unsigned short* s_ = gA + (size_t)((h) * 128) * KK + (tt) * 64;  \
    gload_lds16(s_, &ldsA[sl_]);                                           \
    gload_lds16(s_ + 64 * KK, &ldsA[sl_ + 4096]);                          \
  }
#define STAGE_B(tt, h)                                                     \
  {                                                                        \
    int sl_ = ((2 * (tt) + (h)) & 3) * 8192 + wbase;                       \
    const unsigned short* s_ = gB + (size_t)((h) * 128) * KK + (tt) * 64;  \
    gload_lds16(s_, &ldsB[sl_]);                                           \
    gload_lds16(s_ + 64 * KK, &ldsB[sl_ + 4096]);                          \
  }

  floatx4 acc[8][4];
#pragma unroll
  for (int i = 0; i < 8; i++)
#pragma unroll
    for (int j = 0; j < 4; j++) acc[i][j] = (floatx4){0.f, 0.f, 0.f, 0.f};

  short8 fa0[4][2], fa1[4][2];  // A fragments, mf-groups 0 (rows 0-63) and 1 (rows 64-127)
  short8 fb0[2][2], fb1[2][2];  // B fragments, nf-groups 0 (nf0-1) and 1 (nf2-3)

#define DSRD_A(dst, g)                                                                    \
  _Pragma("unroll") for (int i_ = 0; i_ < 4; i_++) {                                      \
    int ar_ = abase + (((g) * 4 + i_) * 16 + lr) * 64;                                    \
    dst[i_][0] = *(const short8*)&ldsA[ar_ + aoff0];                                      \
    dst[i_][1] = *(const short8*)&ldsA[ar_ + aoff1];                                      \
  }
#define DSRD_B(dst, g)                                                                    \
  _Pragma("unroll") for (int i_ = 0; i_ < 2; i_++) {                                      \
    int br_ = bbase + (rbin + ((g) * 2 + i_) * 16 + lr) * 64;                             \
    dst[i_][0] = *(const short8*)&ldsB[br_ + aoff0];                                      \
    dst[i_][1] = *(const short8*)&ldsB[br_ + aoff1];                                      \
  }
#define MFMAQ2(A_, B_, mg, ng)                                                            \
  __builtin_amdgcn_s_setprio(1);                                                          \
  _Pragma("unroll") for (int i_ = 0; i_ < 4; i_++)                                        \
      _Pragma("unroll") for (int n_ = 0; n_ < 2; n_++)                                    \
          _Pragma("unroll") for (int k_ = 0; k_ < 2; k_++)                                \
              acc[(mg) * 4 + i_][(ng) * 2 + n_] =                                         \
                  __builtin_amdgcn_mfma_f32_16x16x32_bf16(                                \
                      A_[i_][k_], B_[n_][k_], acc[(mg) * 4 + i_][(ng) * 2 + n_], 0, 0, 0); \
  __builtin_amdgcn_s_setprio(0);

#define TILE(tt, doSA1, doSB0, doSB1A0, VM)                      \
  {                                                              \
    int abase = ((2 * (tt) + hA) & 3) * 8192;                    \
    int bbase = ((2 * (tt) + hB) & 3) * 8192;                    \
    /* M0 */                                                     \
    DSRD_A(fa0, 0); DSRD_B(fb0, 0);                              \
    PH_LGKM0(); MFMAQ2(fa0, fb0, 0, 0); DSRD_B(fb1, 1);          \
    PH_BAR();                                                    \
    /* S0 */                                                     \
    if (doSA1) STAGE_A((tt) + 1, 1);                             \
    PH_BAR();                                                    \
    /* M1 */                                                     \
    PH_LGKM0(); MFMAQ2(fa0, fb1, 0, 1); DSRD_A(fa1, 1);          \
    PH_BAR();                                                    \
    /* M2 */                                                     \
    PH_LGKM0(); MFMAQ2(fa1, fb0, 1, 0);                          \
    PH_BAR();                                                    \
    /* S2 */                                                     \
    if (doSB0) STAGE_B((tt) + 2, 0);                             \
    PH_BAR();                                                    \
    /* M3: operands certified at M1/M2 waits */                  \
    MFMAQ2(fa1, fb1, 1, 1);                                      \
    PH_BAR();                                                    \
    /* S3 */                                                     \
    if (doSB1A0) { STAGE_B((tt) + 2, 1); STAGE_A((tt) + 2, 0); } \
    VM;                                                          \
    PH_BAR();                                                    \
  }

  const int NKT = K >> 6;  // 12 for K=768

  // prologue: tile0 (4 halves) + B0,B1,A0 of tile1 = 14 loads; certify tile0
  STAGE_A(0, 0); STAGE_B(0, 0); STAGE_A(0, 1); STAGE_B(0, 1);
  STAGE_B(1, 0); STAGE_B(1, 1); STAGE_A(1, 0);
  WAITV(6);
  PH_BAR();

  for (int tt = 0; tt < NKT - 2; ++tt) TILE(tt, 1, 1, 1, WAITV(6));
  TILE(NKT - 2, 1, 0, 0, WAITV(0));
  TILE(NKT - 1, 0, 0, 0, );

#undef TILE
#undef MFMAQ2
#undef DSRD_A
#undef DSRD_B
#undef STAGE_A
#undef STAGE_B

  // ---------------- epilogue ----------------
  float bv[4];
#pragma unroll
  for (int nf = 0; nf < 4; nf++) bv[nf] = bias[n0 + wn + nf * 16 + lr];

  int part = 0, h = 0;
  float ivf0 = 0.f, ivf1 = 0.f;
  if (MODE == 1) {
    int nbase = n0 + wn;            // wave-uniform, 64-aligned => one head, one part
    part = nbase / ND;
    h = (nbase - part * ND) >> 6;
    ivf0 = __expf(-(float)lr * 0.28782313662425572f);         // invfreq(d=lr)
    ivf1 = __expf(-(float)(16 + lr) * 0.28782313662425572f);  // invfreq(d=16+lr)
  }

#pragma unroll
  for (int mf = 0; mf < 8; mf++) {
#pragma unroll
    for (int r = 0; r < 4; r++) {
      int m = m0 + wm + mf * 16 + lq * 4 + r;  // C/D: row=(lane>>4)*4+reg, col=lane&15
      float fo[4];
#pragma unroll
      for (int nf = 0; nf < 4; nf++) fo[nf] = acc[mf][nf][r] + bv[nf];
      if (MODE == 0) {
#pragma unroll
        for (int nf = 0; nf < 4; nf++)
          out[(size_t)m * N + (n0 + wn + nf * 16 + lr)] = fo[nf];
      } else {
        int b = m >> 9, s = m & 511;
        int bh = b * NH + h;
        if (part == 2) {
#pragma unroll
          for (int nf = 0; nf < 4; nf++)
            Vtg[((size_t)bh * 64 + nf * 16 + lr) * NS + s] = f2bf(fo[nf]);
        } else {
          // fused RoPE: head cols c = nf*16+lr; outputs (d, d+32) need inputs (2d, 2d+1).
          unsigned short* dst = (part ? Kg : Qg) + ((size_t)bh * NS + s) * 64;
          int sl0 = (lq << 4) | ((2 * lr) & 15);
          int sl1 = (lq << 4) | ((2 * lr + 1) & 15);
          float a_l = __shfl(fo[0], sl0), a_h = __shfl(fo[1], sl0);
          float b_l = __shfl(fo[0], sl1), b_h = __shfl(fo[1], sl1);
          float c_l = __shfl(fo[2], sl0), c_h = __shfl(fo[3], sl0);
          float d_l = __shfl(fo[2], sl1), d_h = __shfl(fo[3], sl1);
          bool lo = lr < 8;
          float Av = lo ? a_l : a_h, Bv = lo ? b_l : b_h;   // in(2lr), in(2lr+1)
          float Cv = lo ? c_l : c_h, Dv = lo ? d_l : d_h;   // in(32+2lr), in(33+2lr)
          float fs = (float)s;
          float sn0, cs0, sn1, cs1;
          __sincosf(fs * ivf0, &sn0, &cs0);
          __sincosf(fs * ivf1, &sn1, &cs1);
          dst[lr]      = f2bf(Av * cs0 - Bv * sn0);  // d = lr
          dst[16 + lr] = f2bf(Cv * cs1 - Dv * sn1);  // d = 16+lr
          dst[32 + lr] = f2bf(Av * sn0 + Bv * cs0);  // d+32
          dst[48 + lr] = f2bf(Cv * sn1 + Dv * cs1);  // d+32
        }
      }
    }
  }
}

// ---------------- flash attention: 1 WG = (b,h) x 128 q-rows, 8 waves ----------------
// Grid = (bh, qt=4): bh-major => all blocks of one bh on the same XCD (K/V L2-resident).
// K/V double-buffered via global_load_lds (1 instr per thread per tensor: 64x64 tile =
// 512 lanes x 16B), XOR chunk involution on source + frag reads (linear LDS dest).
// Counted vmcnt(2): next tile's loads issue right after the reuse barrier and fly
// under the current tile's QK/softmax/PV.
__global__ __launch_bounds__(512) void attn_k(
    const unsigned short* __restrict__ Qg, const unsigned short* __restrict__ Kg,
    const unsigned short* __restrict__ Vtg, unsigned short* __restrict__ ctx) {
  __shared__ unsigned short Ks[2][4096];   // 64 rows x 64 cols bf16, chunk-swizzled
  __shared__ unsigned short Vs[2][4096];   // V^T: 64 d-rows x 64 s-cols, chunk-swizzled
  __shared__ unsigned short Ps[8][16 * 72];
  int bh = blockIdx.x, qt = blockIdx.y;
  int t = threadIdx.x, w = t >> 6, lane = t & 63;
  int lr = lane & 15, lq = lane >> 4;
  int q0 = qt * 128 + w * 16;
  const unsigned short* Qb = Qg + (bh * NS + q0) * 64;
  short8 qf0 = *(const short8*)&Qb[lr * 64 + lq * 8];
  short8 qf1 = *(const short8*)&Qb[lr * 64 + 32 + lq * 8];
  floatx4 o[4];
#pragma unroll
  for (int ft = 0; ft < 4; ft++) o[ft] = (floatx4){0.f, 0.f, 0.f, 0.f};
  float m_[4] = {-1e30f, -1e30f, -1e30f, -1e30f};
  float l_[4] = {0.f, 0.f, 0.f, 0.f};

  // stage source: thread t covers row t>>3, phys chunk t&7 = global chunk (t&7)^(row&7)
  int srow = t >> 3;
  int sch = ((t & 7) ^ (srow & 7)) * 8;
  const unsigned short* gK = Kg + bh * NS * 64 + srow * 64 + sch;   // + kt*4096
  const unsigned short* gV = Vtg + bh * 64 * NS + srow * NS + sch;  // + kt*64
  // frag-read chunk offsets (same involution)
  int c0 = (lq ^ (lr & 7)) * 8;
  int c1 = ((4 + lq) ^ (lr & 7)) * 8;

  gload_lds16(gK, &Ks[0][w * 512]);
  gload_lds16(gV, &Vs[0][w * 512]);

  for (int kt = 0; kt < 8; kt++) {
    int cur = kt & 1;
    PH_BAR();  // all waves done reading buf[cur^1] (prev compute) -> safe to overwrite
    if (kt < 7) {
      gload_lds16(gK + (kt + 1) * 4096, &Ks[cur ^ 1][w * 512]);
      gload_lds16(gV + (kt + 1) * 64, &Vs[cur ^ 1][w * 512]);
      WAITV(2);  // cur's 2 loads landed; next's 2 stay in flight
    } else {
      WAITV(0);
    }
    PH_BAR();  // all waves certified buf[cur]

    floatx4 sf[4];
#pragma unroll
    for (int nt = 0; nt < 4; nt++) sf[nt] = (floatx4){0.f, 0.f, 0.f, 0.f};
#pragma unroll
    for (int nt = 0; nt < 4; nt++) {
      short8 k0 = *(const short8*)&Ks[cur][(nt * 16 + lr) * 64 + c0];
      short8 k1 = *(const short8*)&Ks[cur][(nt * 16 + lr) * 64 + c1];
      sf[nt] = __builtin_amdgcn_mfma_f32_16x16x32_bf16(qf0, k0, sf[nt], 0, 0, 0);
      sf[nt] = __builtin_amdgcn_mfma_f32_16x16x32_bf16(qf1, k1, sf[nt], 0, 0, 0);
    }
    float alpha[4];
#pragma unroll
    for (int r = 0; r < 4; r++) {
      float v = fmaxf(fmaxf(sf[0][r], sf[1][r]), fmaxf(sf[2][r], sf[3][r])) * 0.125f;
      v = fmaxf(v, __shfl_xor(v, 1));
      v = fmaxf(v, __shfl_xor(v, 2));
      v = fmaxf(v, __shfl_xor(v, 4));
      v = fmaxf(v, __shfl_xor(v, 8));
      float mn = fmaxf(m_[r], v);
      alpha[r] = __expf(m_[r] - mn);
      m_[r] = mn;
    }
    float rsum[4] = {0.f, 0.f, 0.f, 0.f};
#pragma unroll
    for (int nt = 0; nt < 4; nt++)
#pragma unroll
      for (int r = 0; r < 4; r++) {
        float pv = __expf(sf[nt][r] * 0.125f - m_[r]);
        rsum[r] += pv;
        Ps[w][(lq * 4 + r) * 72 + nt * 16 + lr] = f2bf(pv);
      }
#pragma unroll
    for (int r = 0; r < 4; r++) {
      float v = rsum[r];
      v += __shfl_xor(v, 1);
      v += __shfl_xor(v, 2);
      v += __shfl_xor(v, 4);
      v += __shfl_xor(v, 8);
      l_[r] = l_[r] * alpha[r] + v;
    }
#pragma unroll
    for (int ft = 0; ft < 4; ft++)
#pragma unroll
      for (int r = 0; r < 4; r++) o[ft][r] *= alpha[r];
    // per-wave LDS RAW fence: Ps writes above -> Ps reads below (same wave, diff lanes)
    PH_LGKM0();
#pragma unroll
    for (int ks = 0; ks < 2; ks++) {
      short8 pf = *(const short8*)&Ps[w][lr * 72 + ks * 32 + lq * 8];
      int vco = ks ? c1 : c0;  // logical chunk ks*4+lq, swizzled
#pragma unroll
      for (int ft = 0; ft < 4; ft++) {
        short8 vf = *(const short8*)&Vs[cur][(ft * 16 + lr) * 64 + vco];
        o[ft] = __builtin_amdgcn_mfma_f32_16x16x32_bf16(pf, vf, o[ft], 0, 0, 0);
      }
    }
  }
  int b = bh / NH, h = bh - (bh / NH) * NH;
#pragma unroll
  for (int r = 0; r < 4; r++) {
    float inv = 1.f / l_[r];
#pragma unroll
    for (int ft = 0; ft < 4; ft++)
      ctx[(b * NS + q0 + lq * 4 + r) * ND + h * 64 + ft * 16 + lr] = f2bf(o[ft][r] * inv);
  }
}

extern "C" void kernel_launch(void* const* d_in, const int* in_sizes, int n_in,
                              void* d_out, int out_size, void* d_ws, size_t ws_size,
                              hipStream_t stream) {
  const float* x     = (const float*)d_in[0];   // fp32 (confirmed: bf16 read -> NaN)
  const float* w_qkv = (const float*)d_in[1];   // (768, 2304) fp32
  const float* b_qkv = (const float*)d_in[2];
  const float* w_o   = (const float*)d_in[3];   // (768, 768) fp32
  const float* b_o   = (const float*)d_in[4];
  float* out = (float*)d_out;                   // fp32: reference output dtype

  char* ws = (char*)d_ws;
  unsigned short* xb    = (unsigned short*)(ws);              // x bf16; reused as ctx
  unsigned short* wqkvT = (unsigned short*)(ws + 50331648);   // 2304x768 bf16
  unsigned short* woT   = (unsigned short*)(ws + 53870592);   // 768x768 bf16
  unsigned short* Qg    = (unsigned short*)(ws + 55050240);   // (B,H,S,64) bf16, roped
  unsigned short* Kg    = (unsigned short*)(ws + 105381888);  // roped
  unsigned short* Vtg   = (unsigned short*)(ws + 155713536);
  unsigned short* ctx   = xb;  // x dead after QKV GEMM

  transpose_cvt_k<<<dim3(2304 / 32, 768 / 32), dim3(32, 8), 0, stream>>>(w_qkv, wqkvT, 768, 2304);
  transpose_cvt_k<<<dim3(768 / 32, 768 / 32), dim3(32, 8), 0, stream>>>(w_o, woT, 768, 768);
  convert_k<<<24576, 256, 0, stream>>>(x, xb, 6291456);
  gemm_k<1><<<dim3((32768 / 256) * (2304 / 256)), dim3(512), 0, stream>>>(
      xb, wqkvT, b_qkv, nullptr, Qg, Kg, Vtg, 32768, 2304, 768);
  attn_k<<<dim3(NB * NH, NS / 128), dim3(512), 0, stream>>>(Qg, Kg, Vtg, ctx);
  gemm_k<0><<<dim3((32768 / 256) * (768 / 256)), dim3(512), 0, stream>>>(
      ctx, woT, b_o, out, nullptr, nullptr, nullptr, 32768, 768, 768);
}

// Round 8
// 558.289 us; speedup vs baseline: 1.4688x; 1.0598x over previous
//
#include <hip/hip_runtime.h>
#include <hip/hip_bf16.h>

typedef __attribute__((ext_vector_type(8))) short short8;
typedef __attribute__((ext_vector_type(4))) float floatx4;

#define NB 64
#define NS 512
#define ND 768
#define NH 12

__device__ __forceinline__ float bf2f(unsigned short u) {
  union { unsigned int i; float f; } v; v.i = ((unsigned int)u) << 16; return v.f;
}
__device__ __forceinline__ unsigned short f2bf(float f) {
  union { float f; unsigned int i; } v; v.f = f;
  unsigned int i = v.i;
  unsigned int r = i + 0x7fffu + ((i >> 16) & 1u);
  return (unsigned short)(r >> 16);
}

// async global->LDS, 16B per lane. LDS dest is wave-uniform base + lane*16.
__device__ __forceinline__ void gload_lds16(const unsigned short* g, unsigned short* l) {
  __builtin_amdgcn_global_load_lds(
      (const __attribute__((address_space(1))) unsigned int*)g,
      (__attribute__((address_space(3))) unsigned int*)l, 16, 0, 0);
}

#define WAITV(n) asm volatile("s_waitcnt vmcnt(" #n ")" ::: "memory")
#define PH_BAR() __builtin_amdgcn_s_barrier()
#define CFENCE() asm volatile("" ::: "memory")
#define PH_LGKM0()                                        \
  {                                                       \
    asm volatile("s_waitcnt lgkmcnt(0)" ::: "memory");    \
    __builtin_amdgcn_sched_barrier(0);                    \
  }

// ------- merged prep: transpose+cvt both weight matrices, convert x ----------
// blocks [0,1728): w_qkv^T tiles (72 x 24); [1728,2304): w_o^T tiles (24 x 24);
// [2304, 26880): x fp32 -> bf16, 256 float4 per block.
__global__ void prep_k(const float* __restrict__ w_qkv, unsigned short* __restrict__ wqkvT,
                       const float* __restrict__ w_o, unsigned short* __restrict__ woT,
                       const float* __restrict__ x, unsigned short* __restrict__ xb) {
  __shared__ unsigned short tile[32][33];
  int id = blockIdx.x;
  int tx = threadIdx.x, ty = threadIdx.y;
  if (id < 2304) {
    const float* in;
    unsigned short* out;
    int R, C, bx, by;
    if (id < 1728) { in = w_qkv; out = wqkvT; R = 768; C = 2304; bx = id % 72; by = id / 72; }
    else { int i2 = id - 1728; in = w_o; out = woT; R = 768; C = 768; bx = i2 % 24; by = i2 / 24; }
    int c0 = bx * 32, r0 = by * 32;
#pragma unroll
    for (int i = 0; i < 32; i += 8)
      tile[ty + i][tx] = f2bf(in[(r0 + ty + i) * C + c0 + tx]);
    __syncthreads();
#pragma unroll
    for (int i = 0; i < 32; i += 8) out[(c0 + ty + i) * R + r0 + tx] = tile[tx][ty + i];
  } else {
    int i = (id - 2304) * 256 + ty * 32 + tx;
    if (i < 6291456) {
      float4 v = ((const float4*)x)[i];
      ushort4 o;
      o.x = f2bf(v.x); o.y = f2bf(v.y); o.z = f2bf(v.z); o.w = f2bf(v.w);
      ((ushort4*)xb)[i] = o;
    }
  }
}

// ---------------- GEMM: C = A(MxK bf16) * Bt(NxK bf16)^T + bias(fp32) ----------------
// 128x128 tile, BK=32, 4 waves (2Mx2N), 2-slot LDS double-buffer (32 KiB total),
// counted vmcnt(4) (never 0 mid-loop), raw-barrier 2-phase loop, XOR chunk swizzle
// (stage source + frag read, conflicts=0 verified R2), XCD block swizzle.
// ~3 blocks/CU resident: cross-block wave overlap covers barrier/wait gaps (m114).
// MODE 0: fp32 store. MODE 1: bf16 scatter Q/K (B,H,S,64) with fused RoPE
// (Q additionally pre-scaled by 0.125 so attn skips the scale), Vt (B,H,64,S).
template <int MODE>
__global__ __launch_bounds__(256, 3) void gemm_k(
    const unsigned short* __restrict__ A, const unsigned short* __restrict__ Bt,
    const float* __restrict__ bias, float* __restrict__ out,
    unsigned short* __restrict__ Qg, unsigned short* __restrict__ Kg,
    unsigned short* __restrict__ Vtg, int M, int N, int K) {
  __shared__ unsigned short As[2][128 * 32];  // 2 slots x 8 KB
  __shared__ unsigned short Bs[2][128 * 32];

  // XCD-aware swizzle (nwg % 8 == 0: QKV 4608, proj 1536)
  int nbx = N >> 7;
  int nwg = (M >> 7) * nbx;
  int id = blockIdx.x;
  int q8 = nwg >> 3;
  int wg = (id & 7) * q8 + (id >> 3);
  int bx = wg % nbx, by = wg / nbx;
  int n0 = bx * 128, m0 = by * 128;

  int t = threadIdx.x;
  int w = t >> 6, lane = t & 63;
  int wm = (w >> 1) * 64, wn = (w & 1) * 64;  // wave owns 64x64 of C
  int lr = lane & 15, lq = lane >> 4;

  // staging: thread t covers row t>>2, phys chunk t&3 holds global chunk (t&3)^((t>>3)&3)
  int srow = t >> 2;
  int sch = ((t & 3) ^ ((t >> 3) & 3)) * 8;
  const unsigned short* Ag = A + (size_t)(m0 + srow) * K + sch;
  const unsigned short* Bg = Bt + (size_t)(n0 + srow) * K + sch;
  const size_t rowskip = (size_t)64 * K;
  int ldso = w * 512;

  // frag-read chunk offset (same involution): global chunk lq, row&7 bits -> (lr>>1)&3
  int cs = (lq ^ ((lr >> 1) & 3)) * 8;
  int rA = (wm + lr) * 32 + cs;
  int rB = (wn + lr) * 32 + cs;

  floatx4 acc[4][4];
#pragma unroll
  for (int i = 0; i < 4; i++)
#pragma unroll
    for (int j = 0; j < 4; j++) acc[i][j] = (floatx4){0.f, 0.f, 0.f, 0.f};

  const int NKT = K >> 5;  // 24 for K=768

#define STAGE(kt_)                                                \
  {                                                               \
    int s_ = (kt_) & 1;                                           \
    gload_lds16(Ag + (kt_) * 32, &As[s_][ldso]);                  \
    gload_lds16(Ag + rowskip + (kt_) * 32, &As[s_][2048 + ldso]); \
    gload_lds16(Bg + (kt_) * 32, &Bs[s_][ldso]);                  \
    gload_lds16(Bg + rowskip + (kt_) * 32, &Bs[s_][2048 + ldso]); \
  }

  STAGE(0);
  for (int kt = 0; kt < NKT; ++kt) {
    int cur = kt & 1;
    if (kt + 1 < NKT) {
      STAGE(kt + 1);  // writes slot cur^1; prev iter's trailing barrier certified readers done
      WAITV(4);       // own tile-kt loads landed; (kt+1)'s 4 stay in flight
    } else {
      WAITV(0);
    }
    PH_BAR();  // all waves' tile-kt portions landed
    CFENCE();
    short8 af[4], bfr[4];
#pragma unroll
    for (int mt = 0; mt < 4; mt++) af[mt] = *(const short8*)&As[cur][rA + mt * 512];
#pragma unroll
    for (int nt = 0; nt < 4; nt++) bfr[nt] = *(const short8*)&Bs[cur][rB + nt * 512];
#pragma unroll
    for (int mt = 0; mt < 4; mt++)
#pragma unroll
      for (int nt = 0; nt < 4; nt++)
        acc[mt][nt] = __builtin_amdgcn_mfma_f32_16x16x32_bf16(af[mt], bfr[nt], acc[mt][nt], 0, 0, 0);
    CFENCE();
    PH_BAR();  // all reads done before next iter overwrites slot cur
  }
#undef STAGE

  // ---------------- epilogue ----------------
  float bv[4];
#pragma unroll
  for (int nt = 0; nt < 4; nt++) bv[nt] = bias[n0 + wn + nt * 16 + lr];

  int part = 0, h = 0;
  float ivf0 = 0.f, ivf1 = 0.f, qs = 1.f;
  if (MODE == 1) {
    int nbase = n0 + wn;            // wave-uniform, 64-aligned => one head, one part
    part = nbase / ND;
    h = (nbase - part * ND) >> 6;
    ivf0 = __expf(-(float)lr * 0.28782313662425572f);         // invfreq(d=lr)
    ivf1 = __expf(-(float)(16 + lr) * 0.28782313662425572f);  // invfreq(d=16+lr)
    if (part == 0) qs = 0.125f;     // fold 1/sqrt(dk) into Q
  }

#pragma unroll
  for (int mt = 0; mt < 4; mt++) {
#pragma unroll
    for (int r = 0; r < 4; r++) {
      int m = m0 + wm + mt * 16 + lq * 4 + r;  // C/D: row=(lane>>4)*4+reg, col=lane&15
      float fo[4];
#pragma unroll
      for (int nt = 0; nt < 4; nt++) fo[nt] = acc[mt][nt][r] + bv[nt];
      if (MODE == 0) {
#pragma unroll
        for (int nt = 0; nt < 4; nt++)
          out[(size_t)m * N + (n0 + wn + nt * 16 + lr)] = fo[nt];
      } else {
        int b = m >> 9, s = m & 511;
        int bh = b * NH + h;
        if (part == 2) {
#pragma unroll
          for (int nt = 0; nt < 4; nt++)
            Vtg[((size_t)bh * 64 + nt * 16 + lr) * NS + s] = f2bf(fo[nt]);
        } else {
          // fused RoPE: head cols c = nt*16+lr; outputs (d, d+32) need inputs (2d, 2d+1).
          unsigned short* dst = (part ? Kg : Qg) + ((size_t)bh * NS + s) * 64;
          int sl0 = (lq << 4) | ((2 * lr) & 15);
          int sl1 = (lq << 4) | ((2 * lr + 1) & 15);
          float a_l = __shfl(fo[0], sl0), a_h = __shfl(fo[1], sl0);
          float b_l = __shfl(fo[0], sl1), b_h = __shfl(fo[1], sl1);
          float c_l = __shfl(fo[2], sl0), c_h = __shfl(fo[3], sl0);
          float d_l = __shfl(fo[2], sl1), d_h = __shfl(fo[3], sl1);
          bool lo = lr < 8;
          float Av = lo ? a_l : a_h, Bv = lo ? b_l : b_h;   // in(2lr), in(2lr+1)
          float Cv = lo ? c_l : c_h, Dv = lo ? d_l : d_h;   // in(32+2lr), in(33+2lr)
          float fs = (float)s;
          float sn0, cs0, sn1, cs1;
          __sincosf(fs * ivf0, &sn0, &cs0);
          __sincosf(fs * ivf1, &sn1, &cs1);
          dst[lr]      = f2bf((Av * cs0 - Bv * sn0) * qs);  // d = lr
          dst[16 + lr] = f2bf((Cv * cs1 - Dv * sn1) * qs);  // d = 16+lr
          dst[32 + lr] = f2bf((Av * sn0 + Bv * cs0) * qs);  // d+32
          dst[48 + lr] = f2bf((Cv * sn1 + Dv * cs1) * qs);  // d+32
        }
      }
    }
  }
}

// ---------------- flash attention: 1 WG = (b,h) x 128 q-rows, 8 waves ----------------
// Grid = (bh, qt=4): bh-major => all blocks of one bh on the same XCD (K/V L2-resident).
// K/V double-buffered via global_load_lds, XOR chunk involution, counted vmcnt(2).
// Q is pre-scaled by 0.125 in the QKV epilogue, so scores need no scaling here.
__global__ __launch_bounds__(512) void attn_k(
    const unsigned short* __restrict__ Qg, const unsigned short* __restrict__ Kg,
    const unsigned short* __restrict__ Vtg, unsigned short* __restrict__ ctx) {
  __shared__ unsigned short Ks[2][4096];   // 64 rows x 64 cols bf16, chunk-swizzled
  __shared__ unsigned short Vs[2][4096];   // V^T: 64 d-rows x 64 s-cols, chunk-swizzled
  __shared__ unsigned short Ps[8][16 * 72];
  int bh = blockIdx.x, qt = blockIdx.y;
  int t = threadIdx.x, w = t >> 6, lane = t & 63;
  int lr = lane & 15, lq = lane >> 4;
  int q0 = qt * 128 + w * 16;
  const unsigned short* Qb = Qg + (bh * NS + q0) * 64;
  short8 qf0 = *(const short8*)&Qb[lr * 64 + lq * 8];
  short8 qf1 = *(const short8*)&Qb[lr * 64 + 32 + lq * 8];
  floatx4 o[4];
#pragma unroll
  for (int ft = 0; ft < 4; ft++) o[ft] = (floatx4){0.f, 0.f, 0.f, 0.f};
  float m_[4] = {-1e30f, -1e30f, -1e30f, -1e30f};
  float l_[4] = {0.f, 0.f, 0.f, 0.f};

  int srow = t >> 3;
  int sch = ((t & 7) ^ (srow & 7)) * 8;
  const unsigned short* gK = Kg + bh * NS * 64 + srow * 64 + sch;   // + kt*4096
  const unsigned short* gV = Vtg + bh * 64 * NS + srow * NS + sch;  // + kt*64
  int c0 = (lq ^ (lr & 7)) * 8;
  int c1 = ((4 + lq) ^ (lr & 7)) * 8;

  gload_lds16(gK, &Ks[0][w * 512]);
  gload_lds16(gV, &Vs[0][w * 512]);

  for (int kt = 0; kt < 8; kt++) {
    int cur = kt & 1;
    PH_BAR();  // all waves done reading buf[cur^1] -> safe to overwrite
    if (kt < 7) {
      gload_lds16(gK + (kt + 1) * 4096, &Ks[cur ^ 1][w * 512]);
      gload_lds16(gV + (kt + 1) * 64, &Vs[cur ^ 1][w * 512]);
      WAITV(2);  // cur's 2 loads landed; next's 2 stay in flight
    } else {
      WAITV(0);
    }
    PH_BAR();  // all waves certified buf[cur]

    floatx4 sf[4];
#pragma unroll
    for (int nt = 0; nt < 4; nt++) sf[nt] = (floatx4){0.f, 0.f, 0.f, 0.f};
#pragma unroll
    for (int nt = 0; nt < 4; nt++) {
      short8 k0 = *(const short8*)&Ks[cur][(nt * 16 + lr) * 64 + c0];
      short8 k1 = *(const short8*)&Ks[cur][(nt * 16 + lr) * 64 + c1];
      sf[nt] = __builtin_amdgcn_mfma_f32_16x16x32_bf16(qf0, k0, sf[nt], 0, 0, 0);
      sf[nt] = __builtin_amdgcn_mfma_f32_16x16x32_bf16(qf1, k1, sf[nt], 0, 0, 0);
    }
    float alpha[4];
#pragma unroll
    for (int r = 0; r < 4; r++) {
      float v = fmaxf(fmaxf(sf[0][r], sf[1][r]), fmaxf(sf[2][r], sf[3][r]));
      v = fmaxf(v, __shfl_xor(v, 1));
      v = fmaxf(v, __shfl_xor(v, 2));
      v = fmaxf(v, __shfl_xor(v, 4));
      v = fmaxf(v, __shfl_xor(v, 8));
      float mn = fmaxf(m_[r], v);
      alpha[r] = __expf(m_[r] - mn);
      m_[r] = mn;
    }
    float rsum[4] = {0.f, 0.f, 0.f, 0.f};
#pragma unroll
    for (int nt = 0; nt < 4; nt++)
#pragma unroll
      for (int r = 0; r < 4; r++) {
        float pv = __expf(sf[nt][r] - m_[r]);
        rsum[r] += pv;
        Ps[w][(lq * 4 + r) * 72 + nt * 16 + lr] = f2bf(pv);
      }
#pragma unroll
    for (int r = 0; r < 4; r++) {
      float v = rsum[r];
      v += __shfl_xor(v, 1);
      v += __shfl_xor(v, 2);
      v += __shfl_xor(v, 4);
      v += __shfl_xor(v, 8);
      l_[r] = l_[r] * alpha[r] + v;
    }
#pragma unroll
    for (int ft = 0; ft < 4; ft++)
#pragma unroll
      for (int r = 0; r < 4; r++) o[ft][r] *= alpha[r];
    // per-wave LDS RAW fence: Ps writes above -> Ps reads below (same wave, diff lanes)
    PH_LGKM0();
#pragma unroll
    for (int ks = 0; ks < 2; ks++) {
      short8 pf = *(const short8*)&Ps[w][lr * 72 + ks * 32 + lq * 8];
      int vco = ks ? c1 : c0;  // logical chunk ks*4+lq, swizzled
#pragma unroll
      for (int ft = 0; ft < 4; ft++) {
        short8 vf = *(const short8*)&Vs[cur][(ft * 16 + lr) * 64 + vco];
        o[ft] = __builtin_amdgcn_mfma_f32_16x16x32_bf16(pf, vf, o[ft], 0, 0, 0);
      }
    }
  }
  int b = bh / NH, h = bh - (bh / NH) * NH;
#pragma unroll
  for (int r = 0; r < 4; r++) {
    float inv = 1.f / l_[r];
#pragma unroll
    for (int ft = 0; ft < 4; ft++)
      ctx[(b * NS + q0 + lq * 4 + r) * ND + h * 64 + ft * 16 + lr] = f2bf(o[ft][r] * inv);
  }
}

extern "C" void kernel_launch(void* const* d_in, const int* in_sizes, int n_in,
                              void* d_out, int out_size, void* d_ws, size_t ws_size,
                              hipStream_t stream) {
  const float* x     = (const float*)d_in[0];   // fp32 (confirmed: bf16 read -> NaN)
  const float* w_qkv = (const float*)d_in[1];   // (768, 2304) fp32
  const float* b_qkv = (const float*)d_in[2];
  const float* w_o   = (const float*)d_in[3];   // (768, 768) fp32
  const float* b_o   = (const float*)d_in[4];
  float* out = (float*)d_out;                   // fp32: reference output dtype

  char* ws = (char*)d_ws;
  unsigned short* xb    = (unsigned short*)(ws);              // x bf16; reused as ctx
  unsigned short* wqkvT = (unsigned short*)(ws + 50331648);   // 2304x768 bf16
  unsigned short* woT   = (unsigned short*)(ws + 53870592);   // 768x768 bf16
  unsigned short* Qg    = (unsigned short*)(ws + 55050240);   // (B,H,S,64) bf16, roped+scaled
  unsigned short* Kg    = (unsigned short*)(ws + 105381888);  // roped
  unsigned short* Vtg   = (unsigned short*)(ws + 155713536);
  unsigned short* ctx   = xb;  // x dead after QKV GEMM

  prep_k<<<dim3(26880), dim3(32, 8), 0, stream>>>(w_qkv, wqkvT, w_o, woT, x, xb);
  gemm_k<1><<<dim3(4608), dim3(256), 0, stream>>>(
      xb, wqkvT, b_qkv, nullptr, Qg, Kg, Vtg, 32768, 2304, 768);
  attn_k<<<dim3(NB * NH, NS / 128), dim3(512), 0, stream>>>(Qg, Kg, Vtg, ctx);
  gemm_k<0><<<dim3(1536), dim3(256), 0, stream>>>(
      ctx, woT, b_o, out, nullptr, nullptr, nullptr, 32768, 768, 768);
}